// Round 8
// baseline (57.121 us; speedup 1.0000x reference)
//
#include <hip/hip_runtime.h>
#include <hip/hip_bf16.h>
#include <math.h>

#define BATCH 8
#define LSEQ 2048
#define DM 128
#define NH 4
#define DK 32

constexpr float SCALE = 0.17677669529663687f;   // 1/sqrt(32)
constexpr float LOG2E = 1.4426950408889634f;
constexpr float SL = SCALE * LOG2E;             // folded into Q at qkv store

typedef __attribute__((ext_vector_type(8))) __bf16 bf16x8;
typedef __attribute__((ext_vector_type(16))) float f32x16;
typedef __attribute__((ext_vector_type(2))) unsigned uint2v;

__device__ __forceinline__ bf16x8 as_bf16x8(uint4 u) {
    union { uint4 a; bf16x8 b; } c; c.a = u; return c.b;
}
__device__ __forceinline__ unsigned pack_bf2(float lo, float hi) {
    __hip_bfloat162 h = __float22bfloat162_rn(make_float2(lo, hi));
    union { __hip_bfloat162 a; unsigned b; } c; c.a = h; return c.b;
}

// ---------- kernel 0: per-batch exclusive scan of unmasked keys ----------
__global__ __launch_bounds__(256) void scan_kernel(const float* __restrict__ mask,
                                                   int* __restrict__ cpos,
                                                   int* __restrict__ cnt)
{
    const int b = blockIdx.x;
    const int tid = threadIdx.x;
    __shared__ int ps[256];
    const float* mb = mask + (size_t)b * LSEQ;
    const int base = tid * 8;
    int loc[8];
    int sum = 0;
    #pragma unroll
    for (int i = 0; i < 8; ++i) {
        int u = (mb[base + i] == 0.0f) ? 1 : 0;
        loc[i] = sum;
        sum += u;
    }
    ps[tid] = sum;
    __syncthreads();
    for (int off = 1; off < 256; off <<= 1) {
        int v = (tid >= off) ? ps[tid - off] : 0;
        __syncthreads();
        ps[tid] += v;
        __syncthreads();
    }
    const int prev = (tid > 0) ? ps[tid - 1] : 0;
    #pragma unroll
    for (int i = 0; i < 8; ++i)
        cpos[(size_t)b * LSEQ + base + i] = prev + loc[i];
    if (tid == 255) cnt[b] = ps[255];
}

// ---------- kernel 1: QKV projection via MFMA ----------
// Q is pre-scaled by SCALE*LOG2E so attn can exp2 scores directly.
__global__ __launch_bounds__(256) void qkv_mfma_kernel(const float* __restrict__ x,
    const float* __restrict__ Wq, const float* __restrict__ Wk, const float* __restrict__ Wv,
    const float* __restrict__ mask, const int* __restrict__ cpos,
    unsigned short* __restrict__ Qb, unsigned short* __restrict__ Kb,
    unsigned short* __restrict__ Vcb)
{
    const int b = blockIdx.x;                 // 8
    const int which = blockIdx.y;             // 0=Q 1=K 2=V
    const int lt = blockIdx.z;                // 32 tiles of 64 l
    const int tid = threadIdx.x;
    const int wv = tid >> 6;                  // 4 waves
    const int lane = tid & 63;
    const int ql = lane & 31;
    const int hi = lane >> 5;
    const int l = lt * 64 + (wv & 1) * 32 + ql;   // this lane's output row
    const int hbase = (wv >> 1) * 2;              // head pair

    const float* W = (which == 0 ? Wq : (which == 1 ? Wk : Wv));
    const float* xcol = x + (size_t)b * DM * LSEQ + l;   // x[b][d][l]

    f32x16 acc0, acc1;
    #pragma unroll
    for (int r = 0; r < 16; ++r) { acc0[r] = 0.f; acc1[r] = 0.f; }

    #pragma unroll
    for (int d0 = 0; d0 < DM; d0 += 16) {
        const int dbase = d0 + 8 * hi;
        float xv[8];
        #pragma unroll
        for (int i = 0; i < 8; ++i) xv[i] = xcol[(size_t)(dbase + i) * LSEQ];
        uint4 xp = make_uint4(pack_bf2(xv[0], xv[1]), pack_bf2(xv[2], xv[3]),
                              pack_bf2(xv[4], xv[5]), pack_bf2(xv[6], xv[7]));
        const bf16x8 xf = as_bf16x8(xp);
        const float* wr0 = W + ((size_t)(hbase + 0) * DM + dbase) * DK + ql;
        const float* wr1 = W + ((size_t)(hbase + 1) * DM + dbase) * DK + ql;
        float w0[8], w1[8];
        #pragma unroll
        for (int i = 0; i < 8; ++i) { w0[i] = wr0[i * DK]; w1[i] = wr1[i * DK]; }
        uint4 wp0 = make_uint4(pack_bf2(w0[0], w0[1]), pack_bf2(w0[2], w0[3]),
                               pack_bf2(w0[4], w0[5]), pack_bf2(w0[6], w0[7]));
        uint4 wp1 = make_uint4(pack_bf2(w1[0], w1[1]), pack_bf2(w1[2], w1[3]),
                               pack_bf2(w1[4], w1[5]), pack_bf2(w1[6], w1[7]));
        acc0 = __builtin_amdgcn_mfma_f32_32x32x16_bf16(as_bf16x8(wp0), xf, acc0, 0, 0, 0);
        acc1 = __builtin_amdgcn_mfma_f32_32x32x16_bf16(as_bf16x8(wp1), xf, acc1, 0, 0, 0);
    }

    bool store = true;
    int slot = l;
    if (which != 0) {
        if (mask[(size_t)b * LSEQ + l] == 0.0f) slot = cpos[(size_t)b * LSEQ + l];
        else store = false;
    }
    if (store) {
        const float fold = (which == 0) ? SL : 1.0f;
        unsigned short* base0 = (which == 0 ? Qb : (which == 1 ? Kb : Vcb));
        #pragma unroll
        for (int hh = 0; hh < 2; ++hh) {
            const f32x16& A = hh ? acc1 : acc0;
            const int bh = b * NH + hbase + hh;
            unsigned short* rowp = base0 + ((size_t)bh * LSEQ + slot) * DK;
            unsigned dw[8];
            #pragma unroll
            for (int j = 0; j < 8; ++j) dw[j] = pack_bf2(A[2*j] * fold, A[2*j+1] * fold);
            *reinterpret_cast<uint2*>(rowp + 4*hi)      = make_uint2(dw[0], dw[1]);
            *reinterpret_cast<uint2*>(rowp + 8 + 4*hi)  = make_uint2(dw[2], dw[3]);
            *reinterpret_cast<uint2*>(rowp + 16 + 4*hi) = make_uint2(dw[4], dw[5]);
            *reinterpret_cast<uint2*>(rowp + 24 + 4*hi) = make_uint2(dw[6], dw[7]);
        }
    }
}

// ---------- kernel 1b: Vcb[slot][32] -> V4 MFMA-A-fragment layout ----------
// V4[bh][kt][j][lane][i] = V^T[d=lane&31][key = kt*32 + 16j + 8*(lane>>5) + i]
// so attn's V load is a fully coalesced 1KB wave read: Vp[lane], Vp[64+lane].
__global__ __launch_bounds__(256) void vfrag_kernel(const unsigned short* __restrict__ Vcb,
                                                    unsigned short* __restrict__ V4)
{
    const int bh = blockIdx.y;
    const int s0 = blockIdx.x * 256;            // 256 keys per block (8 k-tiles)
    __shared__ unsigned short lsd[256][34];     // stride 34 u16 -> conflict-light
    const int t = threadIdx.x;
    const uint4* src = reinterpret_cast<const uint4*>(Vcb + ((size_t)bh * LSEQ + s0 + t) * DK);
    uint4 r0 = src[0], r1 = src[1], r2 = src[2], r3 = src[3];
    unsigned* lw = reinterpret_cast<unsigned*>(&lsd[t][0]);   // byte offset t*68, 4B-aligned
    lw[0]=r0.x;  lw[1]=r0.y;  lw[2]=r0.z;  lw[3]=r0.w;
    lw[4]=r1.x;  lw[5]=r1.y;  lw[6]=r1.z;  lw[7]=r1.w;
    lw[8]=r2.x;  lw[9]=r2.y;  lw[10]=r2.z; lw[11]=r2.w;
    lw[12]=r3.x; lw[13]=r3.y; lw[14]=r3.z; lw[15]=r3.w;
    __syncthreads();
    uint4* dst = reinterpret_cast<uint4*>(V4 + (size_t)bh * LSEQ * DK + (size_t)s0 * DK);
    #pragma unroll
    for (int p = 0; p < 4; ++p) {
        const int u = t + 256 * p;              // uint4 index within this 8-kt chunk
        const int ktl = u >> 7;
        const int j = (u >> 6) & 1;
        const int lane = u & 63;
        const int d = lane & 31;
        const int h2 = lane >> 5;
        const int krow = ktl * 32 + 16 * j + 8 * h2;
        unsigned ow[4];
        #pragma unroll
        for (int m = 0; m < 4; ++m) {
            unsigned lo  = lsd[krow + 2*m][d];
            unsigned hi2 = lsd[krow + 2*m + 1][d];
            ow[m] = lo | (hi2 << 16);
        }
        dst[u] = make_uint4(ow[0], ow[1], ow[2], ow[3]);
    }
}

// ---------- kernel 2: MFMA flash attention, 4-way key split ----------
// 2-tile ILP: pairs of tiles with independent accumulators + pair-level
// register prefetch -> two full softmax chains in flight per wave.
__global__ __launch_bounds__(256, 3) void attn_kernel(
    const unsigned short* __restrict__ Qb, const unsigned short* __restrict__ Kb,
    const unsigned short* __restrict__ V4, const float* __restrict__ mask,
    const int* __restrict__ cnt, unsigned short* __restrict__ Hd)
{
    const int bh = blockIdx.y;
    const int b = bh >> 2;
    const int h = bh & 3;
    const int lane = threadIdx.x & 63;
    const int kw = threadIdx.x >> 6;              // key-quarter owner (0..3)
    const int ql = lane & 31;
    const int hi = lane >> 5;
    const int q0 = blockIdx.x * 32;
    const int n = cnt[b];

    const uint4* Qp = reinterpret_cast<const uint4*>(Qb + ((size_t)bh * LSEQ + q0 + ql) * DK);
    const bf16x8 qf0 = as_bf16x8(Qp[hi]);         // Q[q=ql][d=8*hi+i] (pre-scaled)
    const bf16x8 qf1 = as_bf16x8(Qp[2 + hi]);     // d = 16+8*hi+i

    const unsigned short* Kbase = Kb + (size_t)bh * LSEQ * DK;
    const unsigned short* Vb4   = V4 + (size_t)bh * LSEQ * DK;

    f32x16 acc0, acc1;
    #pragma unroll
    for (int r = 0; r < 16; ++r) { acc0[r] = 0.f; acc1[r] = 0.f; }
    f32x16 zero;
    #pragma unroll
    for (int r = 0; r < 16; ++r) zero[r] = 0.f;
    float la0 = 0.f, la1 = 0.f, la2 = 0.f, la3 = 0.f;

    auto ldk0 = [&](int k) { return reinterpret_cast<const uint4*>(Kbase + (size_t)(k + ql) * DK)[hi]; };
    auto ldk1 = [&](int k) { return reinterpret_cast<const uint4*>(Kbase + (size_t)(k + ql) * DK)[2 + hi]; };
    auto ldv0 = [&](int k) { return reinterpret_cast<const uint4*>(Vb4 + (size_t)(k >> 5) * 1024)[lane]; };
    auto ldv1 = [&](int k) { return reinterpret_cast<const uint4*>(Vb4 + (size_t)(k >> 5) * 1024)[64 + lane]; };

    auto compute = [&](uint4 kv0, uint4 kv1, uint4 vv0, uint4 vv1, int k0, bool pred,
                       f32x16& acc, float& laA, float& laB) {
        f32x16 s = __builtin_amdgcn_mfma_f32_32x32x16_bf16(as_bf16x8(kv0), qf0, zero, 0, 0, 0);
        s = __builtin_amdgcn_mfma_f32_32x32x16_bf16(as_bf16x8(kv1), qf1, s, 0, 0, 0);
        unsigned w[8];
        #pragma unroll
        for (int j = 0; j < 8; ++j) {
            float e0 = exp2f(s[2*j]);             // key = k0+(r&3)+8*(r>>2)+4*hi
            float e1 = exp2f(s[2*j+1]);
            if (pred) {
                const int r0 = 2*j, r1 = 2*j + 1;
                if (k0 + (r0 & 3) + 8*(r0 >> 2) + 4*hi >= n) e0 = 0.f;
                if (k0 + (r1 & 3) + 8*(r1 >> 2) + 4*hi >= n) e1 = 0.f;
            }
            laA += e0;
            laB += e1;
            w[j] = pack_bf2(e0, e1);
        }
        // half-exchange via permlane32_swap: one swap fills two output words.
        uint2v p0 = __builtin_amdgcn_permlane32_swap(w[0], w[2], false, false);
        uint2v p1 = __builtin_amdgcn_permlane32_swap(w[1], w[3], false, false);
        uint2v p2 = __builtin_amdgcn_permlane32_swap(w[4], w[6], false, false);
        uint2v p3 = __builtin_amdgcn_permlane32_swap(w[5], w[7], false, false);
        uint4 b0 = make_uint4(p0[0], p1[0], p0[1], p1[1]);
        uint4 b1 = make_uint4(p2[0], p3[0], p2[1], p3[1]);
        acc = __builtin_amdgcn_mfma_f32_32x32x16_bf16(as_bf16x8(vv0), as_bf16x8(b0), acc, 0, 0, 0);
        acc = __builtin_amdgcn_mfma_f32_32x32x16_bf16(as_bf16x8(vv1), as_bf16x8(b1), acc, 0, 0, 0);
    };

    const int nfull = n & ~31;
    int kk = kw * 32;
    int m = (nfull > kk) ? ((nfull - kk + 127) >> 7) : 0;   // my full tiles (spaced 128)

    if (m >= 2) {
        uint4 A0 = ldk0(kk),       A1 = ldk1(kk),       A2 = ldv0(kk),       A3 = ldv1(kk);
        uint4 A4 = ldk0(kk + 128), A5 = ldk1(kk + 128), A6 = ldv0(kk + 128), A7 = ldv1(kk + 128);
        while (m >= 4) {
            uint4 B0 = ldk0(kk + 256), B1 = ldk1(kk + 256), B2 = ldv0(kk + 256), B3 = ldv1(kk + 256);
            uint4 B4 = ldk0(kk + 384), B5 = ldk1(kk + 384), B6 = ldv0(kk + 384), B7 = ldv1(kk + 384);
            compute(A0, A1, A2, A3, kk,       false, acc0, la0, la1);
            compute(A4, A5, A6, A7, kk + 128, false, acc1, la2, la3);
            A0 = B0; A1 = B1; A2 = B2; A3 = B3;
            A4 = B4; A5 = B5; A6 = B6; A7 = B7;
            kk += 256; m -= 2;
        }
        compute(A0, A1, A2, A3, kk,       false, acc0, la0, la1);
        compute(A4, A5, A6, A7, kk + 128, false, acc1, la2, la3);
        kk += 256; m -= 2;
    }
    if (m == 1) {
        uint4 ka0 = ldk0(kk), ka1 = ldk1(kk), va0 = ldv0(kk), va1 = ldv1(kk);
        compute(ka0, ka1, va0, va1, kk, false, acc0, la0, la1);
    }
    if ((n & 31) && (((nfull >> 5) & 3) == kw)) {
        uint4 ka0 = ldk0(nfull), ka1 = ldk1(nfull), va0 = ldv0(nfull), va1 = ldv1(nfull);
        compute(ka0, ka1, va0, va1, nfull, true, acc0, la0, la1);
    }

    // combine dual accumulators, then merge 4 wave-partials via LDS
    #pragma unroll
    for (int r = 0; r < 16; ++r) acc0[r] += acc1[r];
    float lacc = (la0 + la1) + (la2 + la3);

    __shared__ float red[3][64][17];
    if (kw > 0) {
        #pragma unroll
        for (int r = 0; r < 16; ++r) red[kw - 1][lane][r] = acc0[r];
        red[kw - 1][lane][16] = lacc;
    }
    __syncthreads();
    if (kw == 0) {
        #pragma unroll
        for (int c = 0; c < 3; ++c) {
            #pragma unroll
            for (int r = 0; r < 16; ++r) acc0[r] += red[c][lane][r];
            lacc += red[c][lane][16];
        }
        const float lf = lacc + __shfl_xor(lacc, 32);
        const float mq = mask[(size_t)b * LSEQ + q0 + ql];
        const float wgt = (lf > 0.f) ? (mq / lf) : 0.f;
        unsigned short* orow = Hd + ((size_t)b * LSEQ + q0 + ql) * DM + h * DK + 4 * hi;
        #pragma unroll
        for (int g = 0; g < 4; ++g) {            // d = 8g + 4hi + (0..3)
            uint2 p = make_uint2(pack_bf2(acc0[4*g+0]*wgt, acc0[4*g+1]*wgt),
                                 pack_bf2(acc0[4*g+2]*wgt, acc0[4*g+3]*wgt));
            *reinterpret_cast<uint2*>(orow + 8*g) = p;
        }
    }
}

// ---------- kernel 3: output projection via MFMA + transposed store ----------
__global__ __launch_bounds__(256) void proj_mfma_kernel(const unsigned short* __restrict__ Hd,
    const float* __restrict__ Wo, float* __restrict__ out)
{
    const int blk = blockIdx.x;                   // 512 = 8 b x 64 l-tiles
    const int b = blk >> 6;
    const int l0 = (blk & 63) * 32;
    const int tid = threadIdx.x;
    const int jt = tid >> 6;                      // j-tile per wave
    const int lane = tid & 63;
    const int ql = lane & 31;
    const int hi = lane >> 5;

    const unsigned short* hrow = Hd + ((size_t)b * LSEQ + l0 + ql) * DM;

    f32x16 acc;
    #pragma unroll
    for (int r = 0; r < 16; ++r) acc[r] = 0.f;

    #pragma unroll
    for (int ks = 0; ks < 8; ++ks) {
        const int k0 = ks * 16 + 8 * hi;
        uint4 bp = *reinterpret_cast<const uint4*>(hrow + k0);      // Hd[l][k0..k0+7]
        const float* wcol = Wo + (size_t)k0 * DM + jt * 32 + ql;    // Wo[k][j]
        float w[8];
        #pragma unroll
        for (int i = 0; i < 8; ++i) w[i] = wcol[(size_t)i * DM];
        uint4 ap = make_uint4(pack_bf2(w[0], w[1]), pack_bf2(w[2], w[3]),
                              pack_bf2(w[4], w[5]), pack_bf2(w[6], w[7]));
        acc = __builtin_amdgcn_mfma_f32_32x32x16_bf16(as_bf16x8(ap), as_bf16x8(bp), acc, 0, 0, 0);
    }

    float* obase = out + (size_t)b * DM * LSEQ + l0 + ql;
    #pragma unroll
    for (int r = 0; r < 16; ++r) {
        const int j = jt * 32 + (r & 3) + 8 * (r >> 2) + 4 * hi;
        obase[(size_t)j * LSEQ] = acc[r];         // coalesced across ql
    }
}

extern "C" void kernel_launch(void* const* d_in, const int* in_sizes, int n_in,
                              void* d_out, int out_size, void* d_ws, size_t ws_size,
                              hipStream_t stream)
{
    const float* x    = (const float*)d_in[0];
    const float* mask = (const float*)d_in[1];
    const float* Wq   = (const float*)d_in[2];
    const float* Wk   = (const float*)d_in[3];
    const float* Wv   = (const float*)d_in[4];
    const float* Wo   = (const float*)d_in[5];
    float* out = (float*)d_out;

    char* wsb = (char*)d_ws;
    const size_t NBF = (size_t)BATCH * NH * LSEQ * DK;      // 2,097,152 elems
    unsigned short* Qb  = (unsigned short*)wsb;             // 4MB
    unsigned short* Kb  = Qb + NBF;                         // 4MB
    unsigned short* Vcb = Kb + NBF;                         // 4MB
    unsigned short* V4  = Vcb + NBF;                        // 4MB frag-layout V
    unsigned short* Hd  = V4 + NBF;                         // 4MB bf16 (B,L,128)
    int* cpos = (int*)(wsb + 24ull * 1024 * 1024);
    int* cnt  = cpos + (size_t)BATCH * LSEQ;

    scan_kernel<<<dim3(BATCH), dim3(256), 0, stream>>>(mask, cpos, cnt);
    qkv_mfma_kernel<<<dim3(BATCH, 3, LSEQ / 64), dim3(256), 0, stream>>>(
        x, Wq, Wk, Wv, mask, cpos, Qb, Kb, Vcb);
    vfrag_kernel<<<dim3(LSEQ / 256, BATCH * NH), dim3(256), 0, stream>>>(Vcb, V4);
    attn_kernel<<<dim3(LSEQ / 32, BATCH * NH), dim3(256), 0, stream>>>(
        Qb, Kb, V4, mask, cnt, Hd);
    proj_mfma_kernel<<<dim3(BATCH * LSEQ / 32), dim3(256), 0, stream>>>(Hd, Wo, out);
}

// Round 9
// 56.663 us; speedup vs baseline: 1.0081x; 1.0081x over previous
//
#include <hip/hip_runtime.h>
#include <hip/hip_bf16.h>
#include <math.h>

#define BATCH 8
#define LSEQ 2048
#define DM 128
#define NH 4
#define DK 32

constexpr float SCALE = 0.17677669529663687f;   // 1/sqrt(32)
constexpr float LOG2E = 1.4426950408889634f;
constexpr float SL = SCALE * LOG2E;             // folded into Q at qkv store

typedef __attribute__((ext_vector_type(8))) __bf16 bf16x8;
typedef __attribute__((ext_vector_type(16))) float f32x16;
typedef __attribute__((ext_vector_type(2))) unsigned uint2v;

__device__ __forceinline__ bf16x8 as_bf16x8(uint4 u) {
    union { uint4 a; bf16x8 b; } c; c.a = u; return c.b;
}
__device__ __forceinline__ unsigned pack_bf2(float lo, float hi) {
    __hip_bfloat162 h = __float22bfloat162_rn(make_float2(lo, hi));
    union { __hip_bfloat162 a; unsigned b; } c; c.a = h; return c.b;
}

// ---------- kernel 0: per-batch exclusive scan of unmasked keys ----------
__global__ __launch_bounds__(256) void scan_kernel(const float* __restrict__ mask,
                                                   int* __restrict__ cpos,
                                                   int* __restrict__ cnt)
{
    const int b = blockIdx.x;
    const int tid = threadIdx.x;
    __shared__ int ps[256];
    const float* mb = mask + (size_t)b * LSEQ;
    const int base = tid * 8;
    int loc[8];
    int sum = 0;
    #pragma unroll
    for (int i = 0; i < 8; ++i) {
        int u = (mb[base + i] == 0.0f) ? 1 : 0;
        loc[i] = sum;
        sum += u;
    }
    ps[tid] = sum;
    __syncthreads();
    for (int off = 1; off < 256; off <<= 1) {
        int v = (tid >= off) ? ps[tid - off] : 0;
        __syncthreads();
        ps[tid] += v;
        __syncthreads();
    }
    const int prev = (tid > 0) ? ps[tid - 1] : 0;
    #pragma unroll
    for (int i = 0; i < 8; ++i)
        cpos[(size_t)b * LSEQ + base + i] = prev + loc[i];
    if (tid == 255) cnt[b] = ps[255];
}

// ---------- kernel 1: QKV projection via MFMA ----------
// Q is pre-scaled by SCALE*LOG2E so attn can exp2 scores directly.
__global__ __launch_bounds__(256) void qkv_mfma_kernel(const float* __restrict__ x,
    const float* __restrict__ Wq, const float* __restrict__ Wk, const float* __restrict__ Wv,
    const float* __restrict__ mask, const int* __restrict__ cpos,
    unsigned short* __restrict__ Qb, unsigned short* __restrict__ Kb,
    unsigned short* __restrict__ Vcb)
{
    const int b = blockIdx.x;                 // 8
    const int which = blockIdx.y;             // 0=Q 1=K 2=V
    const int lt = blockIdx.z;                // 32 tiles of 64 l
    const int tid = threadIdx.x;
    const int wv = tid >> 6;                  // 4 waves
    const int lane = tid & 63;
    const int ql = lane & 31;
    const int hi = lane >> 5;
    const int l = lt * 64 + (wv & 1) * 32 + ql;   // this lane's output row
    const int hbase = (wv >> 1) * 2;              // head pair

    const float* W = (which == 0 ? Wq : (which == 1 ? Wk : Wv));
    const float* xcol = x + (size_t)b * DM * LSEQ + l;   // x[b][d][l]

    f32x16 acc0, acc1;
    #pragma unroll
    for (int r = 0; r < 16; ++r) { acc0[r] = 0.f; acc1[r] = 0.f; }

    #pragma unroll
    for (int d0 = 0; d0 < DM; d0 += 16) {
        const int dbase = d0 + 8 * hi;
        float xv[8];
        #pragma unroll
        for (int i = 0; i < 8; ++i) xv[i] = xcol[(size_t)(dbase + i) * LSEQ];
        uint4 xp = make_uint4(pack_bf2(xv[0], xv[1]), pack_bf2(xv[2], xv[3]),
                              pack_bf2(xv[4], xv[5]), pack_bf2(xv[6], xv[7]));
        const bf16x8 xf = as_bf16x8(xp);
        const float* wr0 = W + ((size_t)(hbase + 0) * DM + dbase) * DK + ql;
        const float* wr1 = W + ((size_t)(hbase + 1) * DM + dbase) * DK + ql;
        float w0[8], w1[8];
        #pragma unroll
        for (int i = 0; i < 8; ++i) { w0[i] = wr0[i * DK]; w1[i] = wr1[i * DK]; }
        uint4 wp0 = make_uint4(pack_bf2(w0[0], w0[1]), pack_bf2(w0[2], w0[3]),
                               pack_bf2(w0[4], w0[5]), pack_bf2(w0[6], w0[7]));
        uint4 wp1 = make_uint4(pack_bf2(w1[0], w1[1]), pack_bf2(w1[2], w1[3]),
                               pack_bf2(w1[4], w1[5]), pack_bf2(w1[6], w1[7]));
        acc0 = __builtin_amdgcn_mfma_f32_32x32x16_bf16(as_bf16x8(wp0), xf, acc0, 0, 0, 0);
        acc1 = __builtin_amdgcn_mfma_f32_32x32x16_bf16(as_bf16x8(wp1), xf, acc1, 0, 0, 0);
    }

    bool store = true;
    int slot = l;
    if (which != 0) {
        if (mask[(size_t)b * LSEQ + l] == 0.0f) slot = cpos[(size_t)b * LSEQ + l];
        else store = false;
    }
    if (store) {
        const float fold = (which == 0) ? SL : 1.0f;
        unsigned short* base0 = (which == 0 ? Qb : (which == 1 ? Kb : Vcb));
        #pragma unroll
        for (int hh = 0; hh < 2; ++hh) {
            const f32x16& A = hh ? acc1 : acc0;
            const int bh = b * NH + hbase + hh;
            unsigned short* rowp = base0 + ((size_t)bh * LSEQ + slot) * DK;
            unsigned dw[8];
            #pragma unroll
            for (int j = 0; j < 8; ++j) dw[j] = pack_bf2(A[2*j] * fold, A[2*j+1] * fold);
            *reinterpret_cast<uint2*>(rowp + 4*hi)      = make_uint2(dw[0], dw[1]);
            *reinterpret_cast<uint2*>(rowp + 8 + 4*hi)  = make_uint2(dw[2], dw[3]);
            *reinterpret_cast<uint2*>(rowp + 16 + 4*hi) = make_uint2(dw[4], dw[5]);
            *reinterpret_cast<uint2*>(rowp + 24 + 4*hi) = make_uint2(dw[6], dw[7]);
        }
    }
}

// ---------- kernel 1b: Vcb[slot][32] -> V4 MFMA-A-fragment layout ----------
// V4[bh][kt][j][lane][i] = V^T[d=lane&31][key = kt*32 + 16j + 8*(lane>>5) + i]
// so attn's V load is a fully coalesced 1KB wave read: Vp[lane], Vp[64+lane].
__global__ __launch_bounds__(256) void vfrag_kernel(const unsigned short* __restrict__ Vcb,
                                                    unsigned short* __restrict__ V4)
{
    const int bh = blockIdx.y;
    const int s0 = blockIdx.x * 256;            // 256 keys per block (8 k-tiles)
    __shared__ unsigned short lsd[256][34];     // stride 34 u16 -> conflict-light
    const int t = threadIdx.x;
    const uint4* src = reinterpret_cast<const uint4*>(Vcb + ((size_t)bh * LSEQ + s0 + t) * DK);
    uint4 r0 = src[0], r1 = src[1], r2 = src[2], r3 = src[3];
    unsigned* lw = reinterpret_cast<unsigned*>(&lsd[t][0]);   // byte offset t*68, 4B-aligned
    lw[0]=r0.x;  lw[1]=r0.y;  lw[2]=r0.z;  lw[3]=r0.w;
    lw[4]=r1.x;  lw[5]=r1.y;  lw[6]=r1.z;  lw[7]=r1.w;
    lw[8]=r2.x;  lw[9]=r2.y;  lw[10]=r2.z; lw[11]=r2.w;
    lw[12]=r3.x; lw[13]=r3.y; lw[14]=r3.z; lw[15]=r3.w;
    __syncthreads();
    uint4* dst = reinterpret_cast<uint4*>(V4 + (size_t)bh * LSEQ * DK + (size_t)s0 * DK);
    #pragma unroll
    for (int p = 0; p < 4; ++p) {
        const int u = t + 256 * p;              // uint4 index within this 8-kt chunk
        const int ktl = u >> 7;
        const int j = (u >> 6) & 1;
        const int lane = u & 63;
        const int d = lane & 31;
        const int h2 = lane >> 5;
        const int krow = ktl * 32 + 16 * j + 8 * h2;
        unsigned ow[4];
        #pragma unroll
        for (int m = 0; m < 4; ++m) {
            unsigned lo  = lsd[krow + 2*m][d];
            unsigned hi2 = lsd[krow + 2*m + 1][d];
            ow[m] = lo | (hi2 << 16);
        }
        dst[u] = make_uint4(ow[0], ow[1], ow[2], ow[3]);
    }
}

// ---------- kernel 2: MFMA flash attention ----------
// Each wave owns TWO 32-query tiles (64 q) and runs both chains against each
// loaded K/V tile -> K/V L2 traffic halves (arithmetic-intensity doubling).
__global__ __launch_bounds__(256, 3) void attn_kernel(
    const unsigned short* __restrict__ Qb, const unsigned short* __restrict__ Kb,
    const unsigned short* __restrict__ V4, const float* __restrict__ mask,
    const int* __restrict__ cnt, unsigned short* __restrict__ Hd)
{
    const int bh = blockIdx.y;
    const int b = bh >> 2;
    const int h = bh & 3;
    const int lane = threadIdx.x & 63;
    const int kw = threadIdx.x >> 6;              // key-quarter owner (0..3)
    const int ql = lane & 31;
    const int hi = lane >> 5;
    const int q0 = blockIdx.x * 64;
    const int n = cnt[b];

    const uint4* QpA = reinterpret_cast<const uint4*>(Qb + ((size_t)bh * LSEQ + q0 + ql) * DK);
    const uint4* QpB = reinterpret_cast<const uint4*>(Qb + ((size_t)bh * LSEQ + q0 + 32 + ql) * DK);
    const bf16x8 qfA0 = as_bf16x8(QpA[hi]);       // tile A: q = q0+ql
    const bf16x8 qfA1 = as_bf16x8(QpA[2 + hi]);
    const bf16x8 qfB0 = as_bf16x8(QpB[hi]);       // tile B: q = q0+32+ql
    const bf16x8 qfB1 = as_bf16x8(QpB[2 + hi]);

    const unsigned short* Kbase = Kb + (size_t)bh * LSEQ * DK;
    const unsigned short* Vb4   = V4 + (size_t)bh * LSEQ * DK;

    f32x16 accA, accB;
    #pragma unroll
    for (int r = 0; r < 16; ++r) { accA[r] = 0.f; accB[r] = 0.f; }
    f32x16 zero;
    #pragma unroll
    for (int r = 0; r < 16; ++r) zero[r] = 0.f;
    float laA0 = 0.f, laA1 = 0.f, laB0 = 0.f, laB1 = 0.f;

    auto ldk0 = [&](int k) { return reinterpret_cast<const uint4*>(Kbase + (size_t)(k + ql) * DK)[hi]; };
    auto ldk1 = [&](int k) { return reinterpret_cast<const uint4*>(Kbase + (size_t)(k + ql) * DK)[2 + hi]; };
    auto ldv0 = [&](int k) { return reinterpret_cast<const uint4*>(Vb4 + (size_t)(k >> 5) * 1024)[lane]; };
    auto ldv1 = [&](int k) { return reinterpret_cast<const uint4*>(Vb4 + (size_t)(k >> 5) * 1024)[64 + lane]; };

    auto computePair = [&](uint4 kv0, uint4 kv1, uint4 vv0, uint4 vv1, int k0, bool pred) {
        f32x16 sA = __builtin_amdgcn_mfma_f32_32x32x16_bf16(as_bf16x8(kv0), qfA0, zero, 0, 0, 0);
        sA = __builtin_amdgcn_mfma_f32_32x32x16_bf16(as_bf16x8(kv1), qfA1, sA, 0, 0, 0);
        f32x16 sB = __builtin_amdgcn_mfma_f32_32x32x16_bf16(as_bf16x8(kv0), qfB0, zero, 0, 0, 0);
        sB = __builtin_amdgcn_mfma_f32_32x32x16_bf16(as_bf16x8(kv1), qfB1, sB, 0, 0, 0);
        unsigned wA[8], wB[8];
        #pragma unroll
        for (int j = 0; j < 8; ++j) {
            float eA0 = exp2f(sA[2*j]);           // key = k0+(r&3)+8*(r>>2)+4*hi
            float eA1 = exp2f(sA[2*j+1]);
            float eB0 = exp2f(sB[2*j]);
            float eB1 = exp2f(sB[2*j+1]);
            if (pred) {
                const int r0 = 2*j, r1 = 2*j + 1;
                const bool o0 = k0 + (r0 & 3) + 8*(r0 >> 2) + 4*hi >= n;
                const bool o1 = k0 + (r1 & 3) + 8*(r1 >> 2) + 4*hi >= n;
                if (o0) { eA0 = 0.f; eB0 = 0.f; }
                if (o1) { eA1 = 0.f; eB1 = 0.f; }
            }
            laA0 += eA0; laA1 += eA1;
            laB0 += eB0; laB1 += eB1;
            wA[j] = pack_bf2(eA0, eA1);
            wB[j] = pack_bf2(eB0, eB1);
        }
        // half-exchange via permlane32_swap: one swap fills two output words.
        uint2v pA0 = __builtin_amdgcn_permlane32_swap(wA[0], wA[2], false, false);
        uint2v pA1 = __builtin_amdgcn_permlane32_swap(wA[1], wA[3], false, false);
        uint2v pA2 = __builtin_amdgcn_permlane32_swap(wA[4], wA[6], false, false);
        uint2v pA3 = __builtin_amdgcn_permlane32_swap(wA[5], wA[7], false, false);
        uint4 bA0 = make_uint4(pA0[0], pA1[0], pA0[1], pA1[1]);
        uint4 bA1 = make_uint4(pA2[0], pA3[0], pA2[1], pA3[1]);
        accA = __builtin_amdgcn_mfma_f32_32x32x16_bf16(as_bf16x8(vv0), as_bf16x8(bA0), accA, 0, 0, 0);
        accA = __builtin_amdgcn_mfma_f32_32x32x16_bf16(as_bf16x8(vv1), as_bf16x8(bA1), accA, 0, 0, 0);
        uint2v pB0 = __builtin_amdgcn_permlane32_swap(wB[0], wB[2], false, false);
        uint2v pB1 = __builtin_amdgcn_permlane32_swap(wB[1], wB[3], false, false);
        uint2v pB2 = __builtin_amdgcn_permlane32_swap(wB[4], wB[6], false, false);
        uint2v pB3 = __builtin_amdgcn_permlane32_swap(wB[5], wB[7], false, false);
        uint4 bB0 = make_uint4(pB0[0], pB1[0], pB0[1], pB1[1]);
        uint4 bB1 = make_uint4(pB2[0], pB3[0], pB2[1], pB3[1]);
        accB = __builtin_amdgcn_mfma_f32_32x32x16_bf16(as_bf16x8(vv0), as_bf16x8(bB0), accB, 0, 0, 0);
        accB = __builtin_amdgcn_mfma_f32_32x32x16_bf16(as_bf16x8(vv1), as_bf16x8(bB1), accB, 0, 0, 0);
    };

    const int nfull = n & ~31;
    int k = kw * 32;
    if (k < nfull) {
        uint4 ka0 = ldk0(k), ka1 = ldk1(k), va0 = ldv0(k), va1 = ldv1(k);
        for (; k + 128 < nfull; k += 128) {
            uint4 kb0 = ldk0(k + 128), kb1 = ldk1(k + 128);
            uint4 vb0 = ldv0(k + 128), vb1 = ldv1(k + 128);
            computePair(ka0, ka1, va0, va1, k, false);
            ka0 = kb0; ka1 = kb1; va0 = vb0; va1 = vb1;
        }
        computePair(ka0, ka1, va0, va1, k, false);
    }
    if ((n & 31) && (((nfull >> 5) & 3) == kw)) {
        uint4 ka0 = ldk0(nfull), ka1 = ldk1(nfull);
        uint4 va0 = ldv0(nfull), va1 = ldv1(nfull);
        computePair(ka0, ka1, va0, va1, nfull, true);
    }

    float laA = laA0 + laA1;
    float laB = laB0 + laB1;

    // merge 4 wave-partials (pure sums) via LDS; both q-tiles in one round.
    __shared__ float red[3][64][35];              // odd stride -> conflict-free
    if (kw > 0) {
        #pragma unroll
        for (int r = 0; r < 16; ++r) red[kw - 1][lane][r] = accA[r];
        red[kw - 1][lane][16] = laA;
        #pragma unroll
        for (int r = 0; r < 16; ++r) red[kw - 1][lane][17 + r] = accB[r];
        red[kw - 1][lane][33] = laB;
    }
    __syncthreads();
    if (kw == 0) {
        #pragma unroll
        for (int c = 0; c < 3; ++c) {
            #pragma unroll
            for (int r = 0; r < 16; ++r) accA[r] += red[c][lane][r];
            laA += red[c][lane][16];
            #pragma unroll
            for (int r = 0; r < 16; ++r) accB[r] += red[c][lane][17 + r];
            laB += red[c][lane][33];
        }
        const float lfA = laA + __shfl_xor(laA, 32);
        const float lfB = laB + __shfl_xor(laB, 32);
        const float mqA = mask[(size_t)b * LSEQ + q0 + ql];
        const float mqB = mask[(size_t)b * LSEQ + q0 + 32 + ql];
        const float wgtA = (lfA > 0.f) ? (mqA / lfA) : 0.f;
        const float wgtB = (lfB > 0.f) ? (mqB / lfB) : 0.f;
        unsigned short* orowA = Hd + ((size_t)b * LSEQ + q0 + ql) * DM + h * DK + 4 * hi;
        unsigned short* orowB = Hd + ((size_t)b * LSEQ + q0 + 32 + ql) * DM + h * DK + 4 * hi;
        #pragma unroll
        for (int g = 0; g < 4; ++g) {            // d = 8g + 4hi + (0..3)
            uint2 pA = make_uint2(pack_bf2(accA[4*g+0]*wgtA, accA[4*g+1]*wgtA),
                                  pack_bf2(accA[4*g+2]*wgtA, accA[4*g+3]*wgtA));
            *reinterpret_cast<uint2*>(orowA + 8*g) = pA;
            uint2 pB = make_uint2(pack_bf2(accB[4*g+0]*wgtB, accB[4*g+1]*wgtB),
                                  pack_bf2(accB[4*g+2]*wgtB, accB[4*g+3]*wgtB));
            *reinterpret_cast<uint2*>(orowB + 8*g) = pB;
        }
    }
}

// ---------- kernel 3: output projection via MFMA + transposed store ----------
__global__ __launch_bounds__(256) void proj_mfma_kernel(const unsigned short* __restrict__ Hd,
    const float* __restrict__ Wo, float* __restrict__ out)
{
    const int blk = blockIdx.x;                   // 512 = 8 b x 64 l-tiles
    const int b = blk >> 6;
    const int l0 = (blk & 63) * 32;
    const int tid = threadIdx.x;
    const int jt = tid >> 6;                      // j-tile per wave
    const int lane = tid & 63;
    const int ql = lane & 31;
    const int hi = lane >> 5;

    const unsigned short* hrow = Hd + ((size_t)b * LSEQ + l0 + ql) * DM;

    f32x16 acc;
    #pragma unroll
    for (int r = 0; r < 16; ++r) acc[r] = 0.f;

    #pragma unroll
    for (int ks = 0; ks < 8; ++ks) {
        const int k0 = ks * 16 + 8 * hi;
        uint4 bp = *reinterpret_cast<const uint4*>(hrow + k0);      // Hd[l][k0..k0+7]
        const float* wcol = Wo + (size_t)k0 * DM + jt * 32 + ql;    // Wo[k][j]
        float w[8];
        #pragma unroll
        for (int i = 0; i < 8; ++i) w[i] = wcol[(size_t)i * DM];
        uint4 ap = make_uint4(pack_bf2(w[0], w[1]), pack_bf2(w[2], w[3]),
                              pack_bf2(w[4], w[5]), pack_bf2(w[6], w[7]));
        acc = __builtin_amdgcn_mfma_f32_32x32x16_bf16(as_bf16x8(ap), as_bf16x8(bp), acc, 0, 0, 0);
    }

    float* obase = out + (size_t)b * DM * LSEQ + l0 + ql;
    #pragma unroll
    for (int r = 0; r < 16; ++r) {
        const int j = jt * 32 + (r & 3) + 8 * (r >> 2) + 4 * hi;
        obase[(size_t)j * LSEQ] = acc[r];         // coalesced across ql
    }
}

extern "C" void kernel_launch(void* const* d_in, const int* in_sizes, int n_in,
                              void* d_out, int out_size, void* d_ws, size_t ws_size,
                              hipStream_t stream)
{
    const float* x    = (const float*)d_in[0];
    const float* mask = (const float*)d_in[1];
    const float* Wq   = (const float*)d_in[2];
    const float* Wk   = (const float*)d_in[3];
    const float* Wv   = (const float*)d_in[4];
    const float* Wo   = (const float*)d_in[5];
    float* out = (float*)d_out;

    char* wsb = (char*)d_ws;
    const size_t NBF = (size_t)BATCH * NH * LSEQ * DK;      // 2,097,152 elems
    unsigned short* Qb  = (unsigned short*)wsb;             // 4MB
    unsigned short* Kb  = Qb + NBF;                         // 4MB
    unsigned short* Vcb = Kb + NBF;                         // 4MB
    unsigned short* V4  = Vcb + NBF;                        // 4MB frag-layout V
    unsigned short* Hd  = V4 + NBF;                         // 4MB bf16 (B,L,128)
    int* cpos = (int*)(wsb + 24ull * 1024 * 1024);
    int* cnt  = cpos + (size_t)BATCH * LSEQ;

    scan_kernel<<<dim3(BATCH), dim3(256), 0, stream>>>(mask, cpos, cnt);
    qkv_mfma_kernel<<<dim3(BATCH, 3, LSEQ / 64), dim3(256), 0, stream>>>(
        x, Wq, Wk, Wv, mask, cpos, Qb, Kb, Vcb);
    vfrag_kernel<<<dim3(LSEQ / 256, BATCH * NH), dim3(256), 0, stream>>>(Vcb, V4);
    attn_kernel<<<dim3(LSEQ / 64, BATCH * NH), dim3(256), 0, stream>>>(
        Qb, Kb, V4, mask, cnt, Hd);
    proj_mfma_kernel<<<dim3(BATCH * LSEQ / 32), dim3(256), 0, stream>>>(Hd, Wo, out);
}

// Round 10
// 52.540 us; speedup vs baseline: 1.0872x; 1.0785x over previous
//
#include <hip/hip_runtime.h>
#include <hip/hip_bf16.h>
#include <math.h>

#define BATCH 8
#define LSEQ 2048
#define DM 128
#define NH 4
#define DK 32

constexpr float SCALE = 0.17677669529663687f;   // 1/sqrt(32)
constexpr float LOG2E = 1.4426950408889634f;
constexpr float SL = SCALE * LOG2E;             // folded into Q at qkv store

typedef __attribute__((ext_vector_type(8))) __bf16 bf16x8;
typedef __attribute__((ext_vector_type(16))) float f32x16;
typedef __attribute__((ext_vector_type(2))) unsigned uint2v;

__device__ __forceinline__ bf16x8 as_bf16x8(uint4 u) {
    union { uint4 a; bf16x8 b; } c; c.a = u; return c.b;
}
__device__ __forceinline__ unsigned pack_bf2(float lo, float hi) {
    __hip_bfloat162 h = __float22bfloat162_rn(make_float2(lo, hi));
    union { __hip_bfloat162 a; unsigned b; } c; c.a = h; return c.b;
}

// ---------- kernel 1: QKV projection via MFMA, with fused mask-scan ----------
// Q is pre-scaled by SCALE*LOG2E so attn can exp2 scores directly.
// K/V blocks recompute the zero-prefix scan for their own 64-l tile
// (shuffle-based block scan, 2 barriers); (which==1, lt==31) writes cnt[b].
__global__ __launch_bounds__(256) void qkv_mfma_kernel(const float* __restrict__ x,
    const float* __restrict__ Wq, const float* __restrict__ Wk, const float* __restrict__ Wv,
    const float* __restrict__ mask,
    unsigned short* __restrict__ Qb, unsigned short* __restrict__ Kb,
    unsigned short* __restrict__ Vcb, int* __restrict__ cnt)
{
    const int b = blockIdx.x;                 // 8
    const int which = blockIdx.y;             // 0=Q 1=K 2=V
    const int lt = blockIdx.z;                // 32 tiles of 64 l
    const int tid = threadIdx.x;
    const int wv = tid >> 6;                  // 4 waves
    const int lane = tid & 63;
    const int ql = lane & 31;
    const int hi = lane >> 5;
    const int l = lt * 64 + (wv & 1) * 32 + ql;   // this lane's output row
    const int hbase = (wv >> 1) * 2;              // head pair

    // ---- fused scan (K/V blocks only; block-uniform branch) ----
    __shared__ int slotbuf[64];
    __shared__ int wsumI[4];
    if (which != 0) {
        const int nchunk = (lt + 1) * 8;          // 8-elem chunks to cover [0, (lt+1)*64)
        int c = 0;
        if (tid < nchunk) {
            const float* mb = mask + (size_t)b * LSEQ + tid * 8;
            #pragma unroll
            for (int i = 0; i < 8; ++i) c += (mb[i] == 0.0f) ? 1 : 0;
        }
        int inc = c;                               // wave-inclusive scan (64 lanes)
        #pragma unroll
        for (int off = 1; off < 64; off <<= 1) {
            int v = __shfl_up(inc, off);
            if (lane >= off) inc += v;
        }
        if (lane == 63) wsumI[wv] = inc;
        __syncthreads();
        int wpre = 0;
        #pragma unroll
        for (int wN = 0; wN < 4; ++wN) if (wN < wv) wpre += wsumI[wN];
        const int excl = wpre + inc - c;           // exclusive prefix of chunk tid
        if (tid >= lt * 8 && tid < lt * 8 + 8) {   // chunks covering this block's 64 l's
            const float* mb = mask + (size_t)b * LSEQ + tid * 8;
            int run = excl;
            #pragma unroll
            for (int i = 0; i < 8; ++i) {
                slotbuf[(tid - lt * 8) * 8 + i] = run;
                run += (mb[i] == 0.0f) ? 1 : 0;
            }
        }
        if (which == 1 && lt == 31 && tid == 255) cnt[b] = wpre + inc;  // total zeros
        __syncthreads();
    }

    const float* W = (which == 0 ? Wq : (which == 1 ? Wk : Wv));
    const float* xcol = x + (size_t)b * DM * LSEQ + l;   // x[b][d][l]

    f32x16 acc0, acc1;
    #pragma unroll
    for (int r = 0; r < 16; ++r) { acc0[r] = 0.f; acc1[r] = 0.f; }

    #pragma unroll
    for (int d0 = 0; d0 < DM; d0 += 16) {
        const int dbase = d0 + 8 * hi;
        float xv[8];
        #pragma unroll
        for (int i = 0; i < 8; ++i) xv[i] = xcol[(size_t)(dbase + i) * LSEQ];
        uint4 xp = make_uint4(pack_bf2(xv[0], xv[1]), pack_bf2(xv[2], xv[3]),
                              pack_bf2(xv[4], xv[5]), pack_bf2(xv[6], xv[7]));
        const bf16x8 xf = as_bf16x8(xp);
        const float* wr0 = W + ((size_t)(hbase + 0) * DM + dbase) * DK + ql;
        const float* wr1 = W + ((size_t)(hbase + 1) * DM + dbase) * DK + ql;
        float w0[8], w1[8];
        #pragma unroll
        for (int i = 0; i < 8; ++i) { w0[i] = wr0[i * DK]; w1[i] = wr1[i * DK]; }
        uint4 wp0 = make_uint4(pack_bf2(w0[0], w0[1]), pack_bf2(w0[2], w0[3]),
                               pack_bf2(w0[4], w0[5]), pack_bf2(w0[6], w0[7]));
        uint4 wp1 = make_uint4(pack_bf2(w1[0], w1[1]), pack_bf2(w1[2], w1[3]),
                               pack_bf2(w1[4], w1[5]), pack_bf2(w1[6], w1[7]));
        acc0 = __builtin_amdgcn_mfma_f32_32x32x16_bf16(as_bf16x8(wp0), xf, acc0, 0, 0, 0);
        acc1 = __builtin_amdgcn_mfma_f32_32x32x16_bf16(as_bf16x8(wp1), xf, acc1, 0, 0, 0);
    }

    bool store = true;
    int slot = l;
    if (which != 0) {
        if (mask[(size_t)b * LSEQ + l] == 0.0f) slot = slotbuf[(wv & 1) * 32 + ql];
        else store = false;
    }
    if (store) {
        const float fold = (which == 0) ? SL : 1.0f;
        unsigned short* base0 = (which == 0 ? Qb : (which == 1 ? Kb : Vcb));
        #pragma unroll
        for (int hh = 0; hh < 2; ++hh) {
            const f32x16& A = hh ? acc1 : acc0;
            const int bh = b * NH + hbase + hh;
            unsigned short* rowp = base0 + ((size_t)bh * LSEQ + slot) * DK;
            unsigned dw[8];
            #pragma unroll
            for (int j = 0; j < 8; ++j) dw[j] = pack_bf2(A[2*j] * fold, A[2*j+1] * fold);
            *reinterpret_cast<uint2*>(rowp + 4*hi)      = make_uint2(dw[0], dw[1]);
            *reinterpret_cast<uint2*>(rowp + 8 + 4*hi)  = make_uint2(dw[2], dw[3]);
            *reinterpret_cast<uint2*>(rowp + 16 + 4*hi) = make_uint2(dw[4], dw[5]);
            *reinterpret_cast<uint2*>(rowp + 24 + 4*hi) = make_uint2(dw[6], dw[7]);
        }
    }
}

// ---------- kernel 1b: Vcb[slot][32] -> V4 MFMA-A-fragment layout ----------
// V4[bh][kt][j][lane][i] = V^T[d=lane&31][key = kt*32 + 16j + 8*(lane>>5) + i]
// so attn's V load is a fully coalesced 1KB wave read: Vp[lane], Vp[64+lane].
__global__ __launch_bounds__(256) void vfrag_kernel(const unsigned short* __restrict__ Vcb,
                                                    unsigned short* __restrict__ V4)
{
    const int bh = blockIdx.y;
    const int s0 = blockIdx.x * 256;            // 256 keys per block (8 k-tiles)
    __shared__ unsigned short lsd[256][34];     // stride 34 u16 -> conflict-light
    const int t = threadIdx.x;
    const uint4* src = reinterpret_cast<const uint4*>(Vcb + ((size_t)bh * LSEQ + s0 + t) * DK);
    uint4 r0 = src[0], r1 = src[1], r2 = src[2], r3 = src[3];
    unsigned* lw = reinterpret_cast<unsigned*>(&lsd[t][0]);   // byte offset t*68, 4B-aligned
    lw[0]=r0.x;  lw[1]=r0.y;  lw[2]=r0.z;  lw[3]=r0.w;
    lw[4]=r1.x;  lw[5]=r1.y;  lw[6]=r1.z;  lw[7]=r1.w;
    lw[8]=r2.x;  lw[9]=r2.y;  lw[10]=r2.z; lw[11]=r2.w;
    lw[12]=r3.x; lw[13]=r3.y; lw[14]=r3.z; lw[15]=r3.w;
    __syncthreads();
    uint4* dst = reinterpret_cast<uint4*>(V4 + (size_t)bh * LSEQ * DK + (size_t)s0 * DK);
    #pragma unroll
    for (int p = 0; p < 4; ++p) {
        const int u = t + 256 * p;              // uint4 index within this 8-kt chunk
        const int ktl = u >> 7;
        const int j = (u >> 6) & 1;
        const int lane = u & 63;
        const int d = lane & 31;
        const int h2 = lane >> 5;
        const int krow = ktl * 32 + 16 * j + 8 * h2;
        unsigned ow[4];
        #pragma unroll
        for (int m = 0; m < 4; ++m) {
            unsigned lo  = lsd[krow + 2*m][d];
            unsigned hi2 = lsd[krow + 2*m + 1][d];
            ow[m] = lo | (hi2 << 16);
        }
        dst[u] = make_uint4(ow[0], ow[1], ow[2], ow[3]);
    }
}

// ---------- kernel 2: MFMA flash attention ----------
// Each wave owns TWO 32-query tiles (64 q) and runs both chains against each
// loaded K/V tile -> K/V L2 traffic halves (arithmetic-intensity doubling).
__global__ __launch_bounds__(256, 3) void attn_kernel(
    const unsigned short* __restrict__ Qb, const unsigned short* __restrict__ Kb,
    const unsigned short* __restrict__ V4, const float* __restrict__ mask,
    const int* __restrict__ cnt, unsigned short* __restrict__ Hd)
{
    const int bh = blockIdx.y;
    const int b = bh >> 2;
    const int h = bh & 3;
    const int lane = threadIdx.x & 63;
    const int kw = threadIdx.x >> 6;              // key-quarter owner (0..3)
    const int ql = lane & 31;
    const int hi = lane >> 5;
    const int q0 = blockIdx.x * 64;
    const int n = cnt[b];

    const uint4* QpA = reinterpret_cast<const uint4*>(Qb + ((size_t)bh * LSEQ + q0 + ql) * DK);
    const uint4* QpB = reinterpret_cast<const uint4*>(Qb + ((size_t)bh * LSEQ + q0 + 32 + ql) * DK);
    const bf16x8 qfA0 = as_bf16x8(QpA[hi]);       // tile A: q = q0+ql
    const bf16x8 qfA1 = as_bf16x8(QpA[2 + hi]);
    const bf16x8 qfB0 = as_bf16x8(QpB[hi]);       // tile B: q = q0+32+ql
    const bf16x8 qfB1 = as_bf16x8(QpB[2 + hi]);

    const unsigned short* Kbase = Kb + (size_t)bh * LSEQ * DK;
    const unsigned short* Vb4   = V4 + (size_t)bh * LSEQ * DK;

    f32x16 accA, accB;
    #pragma unroll
    for (int r = 0; r < 16; ++r) { accA[r] = 0.f; accB[r] = 0.f; }
    f32x16 zero;
    #pragma unroll
    for (int r = 0; r < 16; ++r) zero[r] = 0.f;
    float laA0 = 0.f, laA1 = 0.f, laB0 = 0.f, laB1 = 0.f;

    auto ldk0 = [&](int k) { return reinterpret_cast<const uint4*>(Kbase + (size_t)(k + ql) * DK)[hi]; };
    auto ldk1 = [&](int k) { return reinterpret_cast<const uint4*>(Kbase + (size_t)(k + ql) * DK)[2 + hi]; };
    auto ldv0 = [&](int k) { return reinterpret_cast<const uint4*>(Vb4 + (size_t)(k >> 5) * 1024)[lane]; };
    auto ldv1 = [&](int k) { return reinterpret_cast<const uint4*>(Vb4 + (size_t)(k >> 5) * 1024)[64 + lane]; };

    auto computePair = [&](uint4 kv0, uint4 kv1, uint4 vv0, uint4 vv1, int k0, bool pred) {
        f32x16 sA = __builtin_amdgcn_mfma_f32_32x32x16_bf16(as_bf16x8(kv0), qfA0, zero, 0, 0, 0);
        sA = __builtin_amdgcn_mfma_f32_32x32x16_bf16(as_bf16x8(kv1), qfA1, sA, 0, 0, 0);
        f32x16 sB = __builtin_amdgcn_mfma_f32_32x32x16_bf16(as_bf16x8(kv0), qfB0, zero, 0, 0, 0);
        sB = __builtin_amdgcn_mfma_f32_32x32x16_bf16(as_bf16x8(kv1), qfB1, sB, 0, 0, 0);
        unsigned wA[8], wB[8];
        #pragma unroll
        for (int j = 0; j < 8; ++j) {
            float eA0 = exp2f(sA[2*j]);           // key = k0+(r&3)+8*(r>>2)+4*hi
            float eA1 = exp2f(sA[2*j+1]);
            float eB0 = exp2f(sB[2*j]);
            float eB1 = exp2f(sB[2*j+1]);
            if (pred) {
                const int r0 = 2*j, r1 = 2*j + 1;
                const bool o0 = k0 + (r0 & 3) + 8*(r0 >> 2) + 4*hi >= n;
                const bool o1 = k0 + (r1 & 3) + 8*(r1 >> 2) + 4*hi >= n;
                if (o0) { eA0 = 0.f; eB0 = 0.f; }
                if (o1) { eA1 = 0.f; eB1 = 0.f; }
            }
            laA0 += eA0; laA1 += eA1;
            laB0 += eB0; laB1 += eB1;
            wA[j] = pack_bf2(eA0, eA1);
            wB[j] = pack_bf2(eB0, eB1);
        }
        // half-exchange via permlane32_swap: one swap fills two output words.
        uint2v pA0 = __builtin_amdgcn_permlane32_swap(wA[0], wA[2], false, false);
        uint2v pA1 = __builtin_amdgcn_permlane32_swap(wA[1], wA[3], false, false);
        uint2v pA2 = __builtin_amdgcn_permlane32_swap(wA[4], wA[6], false, false);
        uint2v pA3 = __builtin_amdgcn_permlane32_swap(wA[5], wA[7], false, false);
        uint4 bA0 = make_uint4(pA0[0], pA1[0], pA0[1], pA1[1]);
        uint4 bA1 = make_uint4(pA2[0], pA3[0], pA2[1], pA3[1]);
        accA = __builtin_amdgcn_mfma_f32_32x32x16_bf16(as_bf16x8(vv0), as_bf16x8(bA0), accA, 0, 0, 0);
        accA = __builtin_amdgcn_mfma_f32_32x32x16_bf16(as_bf16x8(vv1), as_bf16x8(bA1), accA, 0, 0, 0);
        uint2v pB0 = __builtin_amdgcn_permlane32_swap(wB[0], wB[2], false, false);
        uint2v pB1 = __builtin_amdgcn_permlane32_swap(wB[1], wB[3], false, false);
        uint2v pB2 = __builtin_amdgcn_permlane32_swap(wB[4], wB[6], false, false);
        uint2v pB3 = __builtin_amdgcn_permlane32_swap(wB[5], wB[7], false, false);
        uint4 bB0 = make_uint4(pB0[0], pB1[0], pB0[1], pB1[1]);
        uint4 bB1 = make_uint4(pB2[0], pB3[0], pB2[1], pB3[1]);
        accB = __builtin_amdgcn_mfma_f32_32x32x16_bf16(as_bf16x8(vv0), as_bf16x8(bB0), accB, 0, 0, 0);
        accB = __builtin_amdgcn_mfma_f32_32x32x16_bf16(as_bf16x8(vv1), as_bf16x8(bB1), accB, 0, 0, 0);
    };

    const int nfull = n & ~31;
    int k = kw * 32;
    if (k < nfull) {
        uint4 ka0 = ldk0(k), ka1 = ldk1(k), va0 = ldv0(k), va1 = ldv1(k);
        for (; k + 128 < nfull; k += 128) {
            uint4 kb0 = ldk0(k + 128), kb1 = ldk1(k + 128);
            uint4 vb0 = ldv0(k + 128), vb1 = ldv1(k + 128);
            computePair(ka0, ka1, va0, va1, k, false);
            ka0 = kb0; ka1 = kb1; va0 = vb0; va1 = vb1;
        }
        computePair(ka0, ka1, va0, va1, k, false);
    }
    if ((n & 31) && (((nfull >> 5) & 3) == kw)) {
        uint4 ka0 = ldk0(nfull), ka1 = ldk1(nfull);
        uint4 va0 = ldv0(nfull), va1 = ldv1(nfull);
        computePair(ka0, ka1, va0, va1, nfull, true);
    }

    float laA = laA0 + laA1;
    float laB = laB0 + laB1;

    // merge 4 wave-partials (pure sums) via LDS; both q-tiles in one round.
    __shared__ float red[3][64][35];              // odd stride -> conflict-free
    if (kw > 0) {
        #pragma unroll
        for (int r = 0; r < 16; ++r) red[kw - 1][lane][r] = accA[r];
        red[kw - 1][lane][16] = laA;
        #pragma unroll
        for (int r = 0; r < 16; ++r) red[kw - 1][lane][17 + r] = accB[r];
        red[kw - 1][lane][33] = laB;
    }
    __syncthreads();
    if (kw == 0) {
        #pragma unroll
        for (int c = 0; c < 3; ++c) {
            #pragma unroll
            for (int r = 0; r < 16; ++r) accA[r] += red[c][lane][r];
            laA += red[c][lane][16];
            #pragma unroll
            for (int r = 0; r < 16; ++r) accB[r] += red[c][lane][17 + r];
            laB += red[c][lane][33];
        }
        const float lfA = laA + __shfl_xor(laA, 32);
        const float lfB = laB + __shfl_xor(laB, 32);
        const float mqA = mask[(size_t)b * LSEQ + q0 + ql];
        const float mqB = mask[(size_t)b * LSEQ + q0 + 32 + ql];
        const float wgtA = (lfA > 0.f) ? (mqA / lfA) : 0.f;
        const float wgtB = (lfB > 0.f) ? (mqB / lfB) : 0.f;
        unsigned short* orowA = Hd + ((size_t)b * LSEQ + q0 + ql) * DM + h * DK + 4 * hi;
        unsigned short* orowB = Hd + ((size_t)b * LSEQ + q0 + 32 + ql) * DM + h * DK + 4 * hi;
        #pragma unroll
        for (int g = 0; g < 4; ++g) {            // d = 8g + 4hi + (0..3)
            uint2 pA = make_uint2(pack_bf2(accA[4*g+0]*wgtA, accA[4*g+1]*wgtA),
                                  pack_bf2(accA[4*g+2]*wgtA, accA[4*g+3]*wgtA));
            *reinterpret_cast<uint2*>(orowA + 8*g) = pA;
            uint2 pB = make_uint2(pack_bf2(accB[4*g+0]*wgtB, accB[4*g+1]*wgtB),
                                  pack_bf2(accB[4*g+2]*wgtB, accB[4*g+3]*wgtB));
            *reinterpret_cast<uint2*>(orowB + 8*g) = pB;
        }
    }
}

// ---------- kernel 3: output projection via MFMA + transposed store ----------
__global__ __launch_bounds__(256) void proj_mfma_kernel(const unsigned short* __restrict__ Hd,
    const float* __restrict__ Wo, float* __restrict__ out)
{
    const int blk = blockIdx.x;                   // 512 = 8 b x 64 l-tiles
    const int b = blk >> 6;
    const int l0 = (blk & 63) * 32;
    const int tid = threadIdx.x;
    const int jt = tid >> 6;                      // j-tile per wave
    const int lane = tid & 63;
    const int ql = lane & 31;
    const int hi = lane >> 5;

    const unsigned short* hrow = Hd + ((size_t)b * LSEQ + l0 + ql) * DM;

    f32x16 acc;
    #pragma unroll
    for (int r = 0; r < 16; ++r) acc[r] = 0.f;

    #pragma unroll
    for (int ks = 0; ks < 8; ++ks) {
        const int k0 = ks * 16 + 8 * hi;
        uint4 bp = *reinterpret_cast<const uint4*>(hrow + k0);      // Hd[l][k0..k0+7]
        const float* wcol = Wo + (size_t)k0 * DM + jt * 32 + ql;    // Wo[k][j]
        float w[8];
        #pragma unroll
        for (int i = 0; i < 8; ++i) w[i] = wcol[(size_t)i * DM];
        uint4 ap = make_uint4(pack_bf2(w[0], w[1]), pack_bf2(w[2], w[3]),
                              pack_bf2(w[4], w[5]), pack_bf2(w[6], w[7]));
        acc = __builtin_amdgcn_mfma_f32_32x32x16_bf16(as_bf16x8(ap), as_bf16x8(bp), acc, 0, 0, 0);
    }

    float* obase = out + (size_t)b * DM * LSEQ + l0 + ql;
    #pragma unroll
    for (int r = 0; r < 16; ++r) {
        const int j = jt * 32 + (r & 3) + 8 * (r >> 2) + 4 * hi;
        obase[(size_t)j * LSEQ] = acc[r];         // coalesced across ql
    }
}

extern "C" void kernel_launch(void* const* d_in, const int* in_sizes, int n_in,
                              void* d_out, int out_size, void* d_ws, size_t ws_size,
                              hipStream_t stream)
{
    const float* x    = (const float*)d_in[0];
    const float* mask = (const float*)d_in[1];
    const float* Wq   = (const float*)d_in[2];
    const float* Wk   = (const float*)d_in[3];
    const float* Wv   = (const float*)d_in[4];
    const float* Wo   = (const float*)d_in[5];
    float* out = (float*)d_out;

    char* wsb = (char*)d_ws;
    const size_t NBF = (size_t)BATCH * NH * LSEQ * DK;      // 2,097,152 elems
    unsigned short* Qb  = (unsigned short*)wsb;             // 4MB
    unsigned short* Kb  = Qb + NBF;                         // 4MB
    unsigned short* Vcb = Kb + NBF;                         // 4MB
    unsigned short* V4  = Vcb + NBF;                        // 4MB frag-layout V
    unsigned short* Hd  = V4 + NBF;                         // 4MB bf16 (B,L,128)
    int* cnt  = (int*)(wsb + 24ull * 1024 * 1024);

    qkv_mfma_kernel<<<dim3(BATCH, 3, LSEQ / 64), dim3(256), 0, stream>>>(
        x, Wq, Wk, Wv, mask, Qb, Kb, Vcb, cnt);
    vfrag_kernel<<<dim3(LSEQ / 256, BATCH * NH), dim3(256), 0, stream>>>(Vcb, V4);
    attn_kernel<<<dim3(LSEQ / 64, BATCH * NH), dim3(256), 0, stream>>>(
        Qb, Kb, V4, mask, cnt, Hd);
    proj_mfma_kernel<<<dim3(BATCH * LSEQ / 32), dim3(256), 0, stream>>>(Hd, Wo, out);
}

// Round 11
// 50.300 us; speedup vs baseline: 1.1356x; 1.0445x over previous
//
#include <hip/hip_runtime.h>
#include <hip/hip_bf16.h>
#include <math.h>

#define BATCH 8
#define LSEQ 2048
#define DM 128
#define NH 4
#define DK 32

constexpr float SCALE = 0.17677669529663687f;   // 1/sqrt(32)
constexpr float LOG2E = 1.4426950408889634f;
constexpr float SL = SCALE * LOG2E;             // folded into Q at qkv store

typedef __attribute__((ext_vector_type(8))) __bf16 bf16x8;
typedef __attribute__((ext_vector_type(16))) float f32x16;
typedef __attribute__((ext_vector_type(2))) unsigned uint2v;

__device__ __forceinline__ bf16x8 as_bf16x8(uint4 u) {
    union { uint4 a; bf16x8 b; } c; c.a = u; return c.b;
}
__device__ __forceinline__ unsigned pack_bf2(float lo, float hi) {
    __hip_bfloat162 h = __float22bfloat162_rn(make_float2(lo, hi));
    union { __hip_bfloat162 a; unsigned b; } c; c.a = h; return c.b;
}

// ---------- kernel 1: QKV projection via MFMA, with fused mask-scan ----------
// Q is pre-scaled by SCALE*LOG2E so attn can exp2 scores directly.
// K/V blocks recompute the zero-prefix scan for their own 64-l tile
// (shuffle-based block scan, 2 barriers); (which==1, lt==31) writes cnt[b].
__global__ __launch_bounds__(256) void qkv_mfma_kernel(const float* __restrict__ x,
    const float* __restrict__ Wq, const float* __restrict__ Wk, const float* __restrict__ Wv,
    const float* __restrict__ mask,
    unsigned short* __restrict__ Qb, unsigned short* __restrict__ Kb,
    unsigned short* __restrict__ Vcb, int* __restrict__ cnt)
{
    const int b = blockIdx.x;                 // 8
    const int which = blockIdx.y;             // 0=Q 1=K 2=V
    const int lt = blockIdx.z;                // 32 tiles of 64 l
    const int tid = threadIdx.x;
    const int wv = tid >> 6;                  // 4 waves
    const int lane = tid & 63;
    const int ql = lane & 31;
    const int hi = lane >> 5;
    const int l = lt * 64 + (wv & 1) * 32 + ql;   // this lane's output row
    const int hbase = (wv >> 1) * 2;              // head pair

    // ---- fused scan (K/V blocks only; block-uniform branch) ----
    __shared__ int slotbuf[64];
    __shared__ int wsumI[4];
    if (which != 0) {
        const int nchunk = (lt + 1) * 8;          // 8-elem chunks to cover [0, (lt+1)*64)
        int c = 0;
        if (tid < nchunk) {
            const float* mb = mask + (size_t)b * LSEQ + tid * 8;
            #pragma unroll
            for (int i = 0; i < 8; ++i) c += (mb[i] == 0.0f) ? 1 : 0;
        }
        int inc = c;                               // wave-inclusive scan (64 lanes)
        #pragma unroll
        for (int off = 1; off < 64; off <<= 1) {
            int v = __shfl_up(inc, off);
            if (lane >= off) inc += v;
        }
        if (lane == 63) wsumI[wv] = inc;
        __syncthreads();
        int wpre = 0;
        #pragma unroll
        for (int wN = 0; wN < 4; ++wN) if (wN < wv) wpre += wsumI[wN];
        const int excl = wpre + inc - c;           // exclusive prefix of chunk tid
        if (tid >= lt * 8 && tid < lt * 8 + 8) {   // chunks covering this block's 64 l's
            const float* mb = mask + (size_t)b * LSEQ + tid * 8;
            int run = excl;
            #pragma unroll
            for (int i = 0; i < 8; ++i) {
                slotbuf[(tid - lt * 8) * 8 + i] = run;
                run += (mb[i] == 0.0f) ? 1 : 0;
            }
        }
        if (which == 1 && lt == 31 && tid == 255) cnt[b] = wpre + inc;  // total zeros
        __syncthreads();
    }

    const float* W = (which == 0 ? Wq : (which == 1 ? Wk : Wv));
    const float* xcol = x + (size_t)b * DM * LSEQ + l;   // x[b][d][l]

    f32x16 acc0, acc1;
    #pragma unroll
    for (int r = 0; r < 16; ++r) { acc0[r] = 0.f; acc1[r] = 0.f; }

    #pragma unroll
    for (int d0 = 0; d0 < DM; d0 += 16) {
        const int dbase = d0 + 8 * hi;
        float xv[8];
        #pragma unroll
        for (int i = 0; i < 8; ++i) xv[i] = xcol[(size_t)(dbase + i) * LSEQ];
        uint4 xp = make_uint4(pack_bf2(xv[0], xv[1]), pack_bf2(xv[2], xv[3]),
                              pack_bf2(xv[4], xv[5]), pack_bf2(xv[6], xv[7]));
        const bf16x8 xf = as_bf16x8(xp);
        const float* wr0 = W + ((size_t)(hbase + 0) * DM + dbase) * DK + ql;
        const float* wr1 = W + ((size_t)(hbase + 1) * DM + dbase) * DK + ql;
        float w0[8], w1[8];
        #pragma unroll
        for (int i = 0; i < 8; ++i) { w0[i] = wr0[i * DK]; w1[i] = wr1[i * DK]; }
        uint4 wp0 = make_uint4(pack_bf2(w0[0], w0[1]), pack_bf2(w0[2], w0[3]),
                               pack_bf2(w0[4], w0[5]), pack_bf2(w0[6], w0[7]));
        uint4 wp1 = make_uint4(pack_bf2(w1[0], w1[1]), pack_bf2(w1[2], w1[3]),
                               pack_bf2(w1[4], w1[5]), pack_bf2(w1[6], w1[7]));
        acc0 = __builtin_amdgcn_mfma_f32_32x32x16_bf16(as_bf16x8(wp0), xf, acc0, 0, 0, 0);
        acc1 = __builtin_amdgcn_mfma_f32_32x32x16_bf16(as_bf16x8(wp1), xf, acc1, 0, 0, 0);
    }

    bool store = true;
    int slot = l;
    if (which != 0) {
        if (mask[(size_t)b * LSEQ + l] == 0.0f) slot = slotbuf[(wv & 1) * 32 + ql];
        else store = false;
    }
    if (store) {
        const float fold = (which == 0) ? SL : 1.0f;
        unsigned short* base0 = (which == 0 ? Qb : (which == 1 ? Kb : Vcb));
        #pragma unroll
        for (int hh = 0; hh < 2; ++hh) {
            const f32x16& A = hh ? acc1 : acc0;
            const int bh = b * NH + hbase + hh;
            unsigned short* rowp = base0 + ((size_t)bh * LSEQ + slot) * DK;
            unsigned dw[8];
            #pragma unroll
            for (int j = 0; j < 8; ++j) dw[j] = pack_bf2(A[2*j] * fold, A[2*j+1] * fold);
            *reinterpret_cast<uint2*>(rowp + 4*hi)      = make_uint2(dw[0], dw[1]);
            *reinterpret_cast<uint2*>(rowp + 8 + 4*hi)  = make_uint2(dw[2], dw[3]);
            *reinterpret_cast<uint2*>(rowp + 16 + 4*hi) = make_uint2(dw[4], dw[5]);
            *reinterpret_cast<uint2*>(rowp + 24 + 4*hi) = make_uint2(dw[6], dw[7]);
        }
    }
}

// ---------- kernel 1b: Vcb[slot][32] -> V4 MFMA-A-fragment layout ----------
// V4[bh][kt][j][lane][i] = V^T[d=lane&31][key = kt*32 + 16j + 8*(lane>>5) + i]
// so attn's V load is a fully coalesced 1KB wave read: Vp[lane], Vp[64+lane].
__global__ __launch_bounds__(256) void vfrag_kernel(const unsigned short* __restrict__ Vcb,
                                                    unsigned short* __restrict__ V4)
{
    const int bh = blockIdx.y;
    const int s0 = blockIdx.x * 256;            // 256 keys per block (8 k-tiles)
    __shared__ unsigned short lsd[256][34];     // stride 34 u16 -> conflict-light
    const int t = threadIdx.x;
    const uint4* src = reinterpret_cast<const uint4*>(Vcb + ((size_t)bh * LSEQ + s0 + t) * DK);
    uint4 r0 = src[0], r1 = src[1], r2 = src[2], r3 = src[3];
    unsigned* lw = reinterpret_cast<unsigned*>(&lsd[t][0]);   // byte offset t*68, 4B-aligned
    lw[0]=r0.x;  lw[1]=r0.y;  lw[2]=r0.z;  lw[3]=r0.w;
    lw[4]=r1.x;  lw[5]=r1.y;  lw[6]=r1.z;  lw[7]=r1.w;
    lw[8]=r2.x;  lw[9]=r2.y;  lw[10]=r2.z; lw[11]=r2.w;
    lw[12]=r3.x; lw[13]=r3.y; lw[14]=r3.z; lw[15]=r3.w;
    __syncthreads();
    uint4* dst = reinterpret_cast<uint4*>(V4 + (size_t)bh * LSEQ * DK + (size_t)s0 * DK);
    #pragma unroll
    for (int p = 0; p < 4; ++p) {
        const int u = t + 256 * p;              // uint4 index within this 8-kt chunk
        const int ktl = u >> 7;
        const int j = (u >> 6) & 1;
        const int lane = u & 63;
        const int d = lane & 31;
        const int h2 = lane >> 5;
        const int krow = ktl * 32 + 16 * j + 8 * h2;
        unsigned ow[4];
        #pragma unroll
        for (int m = 0; m < 4; ++m) {
            unsigned lo  = lsd[krow + 2*m][d];
            unsigned hi2 = lsd[krow + 2*m + 1][d];
            ow[m] = lo | (hi2 << 16);
        }
        dst[u] = make_uint4(ow[0], ow[1], ow[2], ow[3]);
    }
}

// ---------- kernel 2: fused MFMA flash attention + output projection ----------
// Block = (b, 32-query tile), 512 thr = 8 waves = (head, key-half).
// Attn phase: R6-proven single-tile register pipeline per wave.
// Merge: one LDS round (kw==1 -> kw==0). Then heads' O-tiles staged in LDS
// (bf16, row stride 136 for alignment), and waves 0-3 run the proj MFMA.
__global__ __launch_bounds__(512, 4) void attnproj_kernel(
    const unsigned short* __restrict__ Qb, const unsigned short* __restrict__ Kb,
    const unsigned short* __restrict__ V4, const float* __restrict__ mask,
    const int* __restrict__ cnt, const float* __restrict__ Wo,
    float* __restrict__ out)
{
    const int b = blockIdx.y;
    const int q0 = blockIdx.x * 32;
    const int tid = threadIdx.x;
    const int wid = tid >> 6;                     // 8 waves
    const int h = wid >> 1;                       // head
    const int kw = wid & 1;                       // key-half owner
    const int lane = tid & 63;
    const int ql = lane & 31;
    const int hi = lane >> 5;
    const int bh = b * NH + h;
    const int n = cnt[b];

    __shared__ __align__(16) char smem[17408];
    float* red = reinterpret_cast<float*>(smem);                  // [4][64][17]
    unsigned short* hd = reinterpret_cast<unsigned short*>(smem); // [32][136]

    const uint4* Qp = reinterpret_cast<const uint4*>(Qb + ((size_t)bh * LSEQ + q0 + ql) * DK);
    const bf16x8 qf0 = as_bf16x8(Qp[hi]);         // Q[q=ql][d=8*hi+i] (pre-scaled)
    const bf16x8 qf1 = as_bf16x8(Qp[2 + hi]);

    const unsigned short* Kbase = Kb + (size_t)bh * LSEQ * DK;
    const unsigned short* Vb4   = V4 + (size_t)bh * LSEQ * DK;

    f32x16 acc;
    #pragma unroll
    for (int r = 0; r < 16; ++r) acc[r] = 0.f;
    f32x16 zero;
    #pragma unroll
    for (int r = 0; r < 16; ++r) zero[r] = 0.f;
    float la0 = 0.f, la1 = 0.f;

    auto ldk0 = [&](int k) { return reinterpret_cast<const uint4*>(Kbase + (size_t)(k + ql) * DK)[hi]; };
    auto ldk1 = [&](int k) { return reinterpret_cast<const uint4*>(Kbase + (size_t)(k + ql) * DK)[2 + hi]; };
    auto ldv0 = [&](int k) { return reinterpret_cast<const uint4*>(Vb4 + (size_t)(k >> 5) * 1024)[lane]; };
    auto ldv1 = [&](int k) { return reinterpret_cast<const uint4*>(Vb4 + (size_t)(k >> 5) * 1024)[64 + lane]; };

    auto compute = [&](uint4 kv0, uint4 kv1, uint4 vv0, uint4 vv1, int k0, bool pred) {
        f32x16 s = __builtin_amdgcn_mfma_f32_32x32x16_bf16(as_bf16x8(kv0), qf0, zero, 0, 0, 0);
        s = __builtin_amdgcn_mfma_f32_32x32x16_bf16(as_bf16x8(kv1), qf1, s, 0, 0, 0);
        unsigned w[8];
        #pragma unroll
        for (int j = 0; j < 8; ++j) {
            float e0 = exp2f(s[2*j]);             // key = k0+(r&3)+8*(r>>2)+4*hi
            float e1 = exp2f(s[2*j+1]);
            if (pred) {
                const int r0 = 2*j, r1 = 2*j + 1;
                if (k0 + (r0 & 3) + 8*(r0 >> 2) + 4*hi >= n) e0 = 0.f;
                if (k0 + (r1 & 3) + 8*(r1 >> 2) + 4*hi >= n) e1 = 0.f;
            }
            la0 += e0;
            la1 += e1;
            w[j] = pack_bf2(e0, e1);
        }
        uint2v p0 = __builtin_amdgcn_permlane32_swap(w[0], w[2], false, false);
        uint2v p1 = __builtin_amdgcn_permlane32_swap(w[1], w[3], false, false);
        uint2v p2 = __builtin_amdgcn_permlane32_swap(w[4], w[6], false, false);
        uint2v p3 = __builtin_amdgcn_permlane32_swap(w[5], w[7], false, false);
        uint4 b0 = make_uint4(p0[0], p1[0], p0[1], p1[1]);
        uint4 b1 = make_uint4(p2[0], p3[0], p2[1], p3[1]);
        acc = __builtin_amdgcn_mfma_f32_32x32x16_bf16(as_bf16x8(vv0), as_bf16x8(b0), acc, 0, 0, 0);
        acc = __builtin_amdgcn_mfma_f32_32x32x16_bf16(as_bf16x8(vv1), as_bf16x8(b1), acc, 0, 0, 0);
    };

    const int nfull = n & ~31;
    int k = kw * 32;
    if (k < nfull) {
        uint4 ka0 = ldk0(k), ka1 = ldk1(k), va0 = ldv0(k), va1 = ldv1(k);
        for (; k + 64 < nfull; k += 64) {
            uint4 kb0 = ldk0(k + 64), kb1 = ldk1(k + 64);
            uint4 vb0 = ldv0(k + 64), vb1 = ldv1(k + 64);
            compute(ka0, ka1, va0, va1, k, false);
            ka0 = kb0; ka1 = kb1; va0 = vb0; va1 = vb1;
        }
        compute(ka0, ka1, va0, va1, k, false);
    }
    if ((n & 31) && (((nfull >> 5) & 1) == kw)) {
        uint4 ka0 = ldk0(nfull), ka1 = ldk1(nfull);
        uint4 va0 = ldv0(nfull), va1 = ldv1(nfull);
        compute(ka0, ka1, va0, va1, nfull, true);
    }

    float la = la0 + la1;

    // ---- merge the two key-half partials (one LDS round) ----
    if (kw == 1) {
        float* r0 = red + ((size_t)h * 64 + lane) * 17;
        #pragma unroll
        for (int r = 0; r < 16; ++r) r0[r] = acc[r];
        r0[16] = la;
    }
    __syncthreads();
    float wgt = 0.f;
    if (kw == 0) {
        const float* r0 = red + ((size_t)h * 64 + lane) * 17;
        #pragma unroll
        for (int r = 0; r < 16; ++r) acc[r] += r0[r];
        la += r0[16];
        const float lf = la + __shfl_xor(la, 32);
        const float mq = mask[(size_t)b * LSEQ + q0 + ql];
        wgt = (lf > 0.f) ? (mq / lf) : 0.f;
    }
    __syncthreads();                              // red dead; reuse as hd

    // ---- stage normalized O-tile (32 q x 128 d) in LDS as bf16 ----
    if (kw == 0) {
        unsigned short* hrow = hd + ql * 136 + h * DK + 4 * hi;
        #pragma unroll
        for (int g = 0; g < 4; ++g) {             // d = 8g + 4hi + (0..3)
            uint2 p = make_uint2(pack_bf2(acc[4*g+0]*wgt, acc[4*g+1]*wgt),
                                 pack_bf2(acc[4*g+2]*wgt, acc[4*g+3]*wgt));
            *reinterpret_cast<uint2*>(hrow + 8*g) = p;
        }
    }
    __syncthreads();

    // ---- output projection: waves 0-3, one j-quarter each ----
    if (wid < 4) {
        const int jq = wid;
        f32x16 pacc;
        #pragma unroll
        for (int r = 0; r < 16; ++r) pacc[r] = 0.f;
        #pragma unroll
        for (int ks = 0; ks < 8; ++ks) {
            const int k0 = ks * 16 + 8 * hi;
            uint4 bp = *reinterpret_cast<const uint4*>(hd + ql * 136 + k0);  // Hd[l][k0..k0+7]
            const float* wcol = Wo + (size_t)k0 * DM + jq * 32 + ql;         // Wo[k][j]
            float w[8];
            #pragma unroll
            for (int i = 0; i < 8; ++i) w[i] = wcol[(size_t)i * DM];
            uint4 ap = make_uint4(pack_bf2(w[0], w[1]), pack_bf2(w[2], w[3]),
                                  pack_bf2(w[4], w[5]), pack_bf2(w[6], w[7]));
            pacc = __builtin_amdgcn_mfma_f32_32x32x16_bf16(as_bf16x8(ap), as_bf16x8(bp), pacc, 0, 0, 0);
        }
        float* obase = out + (size_t)b * DM * LSEQ + q0 + ql;
        #pragma unroll
        for (int r = 0; r < 16; ++r) {
            const int j = jq * 32 + (r & 3) + 8 * (r >> 2) + 4 * hi;
            obase[(size_t)j * LSEQ] = pacc[r];    // coalesced across ql
        }
    }
}

extern "C" void kernel_launch(void* const* d_in, const int* in_sizes, int n_in,
                              void* d_out, int out_size, void* d_ws, size_t ws_size,
                              hipStream_t stream)
{
    const float* x    = (const float*)d_in[0];
    const float* mask = (const float*)d_in[1];
    const float* Wq   = (const float*)d_in[2];
    const float* Wk   = (const float*)d_in[3];
    const float* Wv   = (const float*)d_in[4];
    const float* Wo   = (const float*)d_in[5];
    float* out = (float*)d_out;

    char* wsb = (char*)d_ws;
    const size_t NBF = (size_t)BATCH * NH * LSEQ * DK;      // 2,097,152 elems
    unsigned short* Qb  = (unsigned short*)wsb;             // 4MB
    unsigned short* Kb  = Qb + NBF;                         // 4MB
    unsigned short* Vcb = Kb + NBF;                         // 4MB
    unsigned short* V4  = Vcb + NBF;                        // 4MB frag-layout V
    int* cnt  = (int*)(wsb + 24ull * 1024 * 1024);

    qkv_mfma_kernel<<<dim3(BATCH, 3, LSEQ / 64), dim3(256), 0, stream>>>(
        x, Wq, Wk, Wv, mask, Qb, Kb, Vcb, cnt);
    vfrag_kernel<<<dim3(LSEQ / 256, BATCH * NH), dim3(256), 0, stream>>>(Vcb, V4);
    attnproj_kernel<<<dim3(LSEQ / 32, BATCH), dim3(512), 0, stream>>>(
        Qb, Kb, V4, mask, cnt, Wo, out);
}

// Round 12
// 46.370 us; speedup vs baseline: 1.2319x; 1.0848x over previous
//
#include <hip/hip_runtime.h>
#include <hip/hip_bf16.h>
#include <math.h>

#define BATCH 8
#define LSEQ 2048
#define DM 128
#define NH 4
#define DK 32

constexpr float SCALE = 0.17677669529663687f;   // 1/sqrt(32)
constexpr float LOG2E = 1.4426950408889634f;
constexpr float SL = SCALE * LOG2E;             // folded into Q at qkv store

typedef __attribute__((ext_vector_type(8))) __bf16 bf16x8;
typedef __attribute__((ext_vector_type(16))) float f32x16;
typedef __attribute__((ext_vector_type(2))) unsigned uint2v;

__device__ __forceinline__ bf16x8 as_bf16x8(uint4 u) {
    union { uint4 a; bf16x8 b; } c; c.a = u; return c.b;
}
__device__ __forceinline__ unsigned pack_bf2(float lo, float hi) {
    __hip_bfloat162 h = __float22bfloat162_rn(make_float2(lo, hi));
    union { __hip_bfloat162 a; unsigned b; } c; c.a = h; return c.b;
}
__device__ __forceinline__ unsigned short bf16u(float f) {
    union { __hip_bfloat16 h; unsigned short u; } c; c.h = __float2bfloat16(f); return c.u;
}

// ---------- kernel 1: QKV projection via MFMA, fused mask-scan, LDS-staged W ----------
// Q is pre-scaled by SCALE*LOG2E so attn can exp2 scores directly.
// W for this block's `which` (all 4 heads, 16K floats) is staged ONCE into LDS
// in MFMA-A-fragment order wl[h][dblk][dk][i] (bf16): the hot loop reads each
// wave's two A-frags as conflict-free ds_read_b128 instead of 16 scalar VMEM.
__global__ __launch_bounds__(256) void qkv_mfma_kernel(const float* __restrict__ x,
    const float* __restrict__ Wq, const float* __restrict__ Wk, const float* __restrict__ Wv,
    const float* __restrict__ mask,
    unsigned short* __restrict__ Qb, unsigned short* __restrict__ Kb,
    unsigned short* __restrict__ Vcb, int* __restrict__ cnt)
{
    const int b = blockIdx.x;                 // 8
    const int which = blockIdx.y;             // 0=Q 1=K 2=V
    const int lt = blockIdx.z;                // 32 tiles of 64 l
    const int tid = threadIdx.x;
    const int wv = tid >> 6;                  // 4 waves
    const int lane = tid & 63;
    const int ql = lane & 31;
    const int hi = lane >> 5;
    const int l = lt * 64 + (wv & 1) * 32 + ql;   // this lane's output row
    const int hbase = (wv >> 1) * 2;              // head pair

    __shared__ unsigned short wl[4][16][32][8];   // 32KB: [h][d/8][dk][d%7+1]
    __shared__ int slotbuf[64];
    __shared__ int wsumI[4];

    const float* W = (which == 0 ? Wq : (which == 1 ? Wk : Wv));

    // ---- one-time W stage: 16384 floats, coalesced float4, frag-order bf16 ----
    #pragma unroll
    for (int it = 0; it < 16; ++it) {
        const int flat = (it * 256 + tid) * 4;    // float index into W[which]
        float4 v = *reinterpret_cast<const float4*>(W + flat);
        const int dk0 = flat & 31;
        const int d   = (flat >> 5) & 127;
        const int h   = flat >> 12;
        wl[h][d >> 3][dk0 + 0][d & 7] = bf16u(v.x);
        wl[h][d >> 3][dk0 + 1][d & 7] = bf16u(v.y);
        wl[h][d >> 3][dk0 + 2][d & 7] = bf16u(v.z);
        wl[h][d >> 3][dk0 + 3][d & 7] = bf16u(v.w);
    }

    // ---- fused scan (K/V blocks only; block-uniform branch) ----
    if (which != 0) {
        const int nchunk = (lt + 1) * 8;          // 8-elem chunks to cover [0, (lt+1)*64)
        int c = 0;
        if (tid < nchunk) {
            const float* mb = mask + (size_t)b * LSEQ + tid * 8;
            #pragma unroll
            for (int i = 0; i < 8; ++i) c += (mb[i] == 0.0f) ? 1 : 0;
        }
        int inc = c;                               // wave-inclusive scan (64 lanes)
        #pragma unroll
        for (int off = 1; off < 64; off <<= 1) {
            int v = __shfl_up(inc, off);
            if (lane >= off) inc += v;
        }
        if (lane == 63) wsumI[wv] = inc;
        __syncthreads();
        int wpre = 0;
        #pragma unroll
        for (int wN = 0; wN < 4; ++wN) if (wN < wv) wpre += wsumI[wN];
        const int excl = wpre + inc - c;           // exclusive prefix of chunk tid
        if (tid >= lt * 8 && tid < lt * 8 + 8) {   // chunks covering this block's 64 l's
            const float* mb = mask + (size_t)b * LSEQ + tid * 8;
            int run = excl;
            #pragma unroll
            for (int i = 0; i < 8; ++i) {
                slotbuf[(tid - lt * 8) * 8 + i] = run;
                run += (mb[i] == 0.0f) ? 1 : 0;
            }
        }
        if (which == 1 && lt == 31 && tid == 255) cnt[b] = wpre + inc;  // total zeros
    }
    __syncthreads();                               // covers W stage (+scan)

    const float* xcol = x + (size_t)b * DM * LSEQ + l;   // x[b][d][l]

    f32x16 acc0, acc1;
    #pragma unroll
    for (int r = 0; r < 16; ++r) { acc0[r] = 0.f; acc1[r] = 0.f; }

    #pragma unroll
    for (int d0 = 0; d0 < DM; d0 += 16) {
        const int dblk = (d0 >> 3) + hi;
        float xv[8];
        #pragma unroll
        for (int i = 0; i < 8; ++i) xv[i] = xcol[(size_t)(d0 + 8 * hi + i) * LSEQ];
        uint4 xp = make_uint4(pack_bf2(xv[0], xv[1]), pack_bf2(xv[2], xv[3]),
                              pack_bf2(xv[4], xv[5]), pack_bf2(xv[6], xv[7]));
        const bf16x8 xf = as_bf16x8(xp);
        uint4 wp0 = *reinterpret_cast<const uint4*>(&wl[hbase + 0][dblk][ql][0]);
        uint4 wp1 = *reinterpret_cast<const uint4*>(&wl[hbase + 1][dblk][ql][0]);
        acc0 = __builtin_amdgcn_mfma_f32_32x32x16_bf16(as_bf16x8(wp0), xf, acc0, 0, 0, 0);
        acc1 = __builtin_amdgcn_mfma_f32_32x32x16_bf16(as_bf16x8(wp1), xf, acc1, 0, 0, 0);
    }

    bool store = true;
    int slot = l;
    if (which != 0) {
        if (mask[(size_t)b * LSEQ + l] == 0.0f) slot = slotbuf[(wv & 1) * 32 + ql];
        else store = false;
    }
    if (store) {
        const float fold = (which == 0) ? SL : 1.0f;
        unsigned short* base0 = (which == 0 ? Qb : (which == 1 ? Kb : Vcb));
        #pragma unroll
        for (int hh = 0; hh < 2; ++hh) {
            const f32x16& A = hh ? acc1 : acc0;
            const int bh = b * NH + hbase + hh;
            unsigned short* rowp = base0 + ((size_t)bh * LSEQ + slot) * DK;
            unsigned dw[8];
            #pragma unroll
            for (int j = 0; j < 8; ++j) dw[j] = pack_bf2(A[2*j] * fold, A[2*j+1] * fold);
            *reinterpret_cast<uint2*>(rowp + 4*hi)      = make_uint2(dw[0], dw[1]);
            *reinterpret_cast<uint2*>(rowp + 8 + 4*hi)  = make_uint2(dw[2], dw[3]);
            *reinterpret_cast<uint2*>(rowp + 16 + 4*hi) = make_uint2(dw[4], dw[5]);
            *reinterpret_cast<uint2*>(rowp + 24 + 4*hi) = make_uint2(dw[6], dw[7]);
        }
    }
}

// ---------- kernel 1b: Vcb[slot][32] -> V4 MFMA-A-fragment layout ----------
// V4[bh][kt][j][lane][i] = V^T[d=lane&31][key = kt*32 + 16j + 8*(lane>>5) + i]
// so attn's V load is a fully coalesced 1KB wave read: Vp[lane], Vp[64+lane].
__global__ __launch_bounds__(256) void vfrag_kernel(const unsigned short* __restrict__ Vcb,
                                                    unsigned short* __restrict__ V4)
{
    const int bh = blockIdx.y;
    const int s0 = blockIdx.x * 256;            // 256 keys per block (8 k-tiles)
    __shared__ unsigned short lsd[256][34];     // stride 34 u16 -> conflict-light
    const int t = threadIdx.x;
    const uint4* src = reinterpret_cast<const uint4*>(Vcb + ((size_t)bh * LSEQ + s0 + t) * DK);
    uint4 r0 = src[0], r1 = src[1], r2 = src[2], r3 = src[3];
    unsigned* lw = reinterpret_cast<unsigned*>(&lsd[t][0]);   // byte offset t*68, 4B-aligned
    lw[0]=r0.x;  lw[1]=r0.y;  lw[2]=r0.z;  lw[3]=r0.w;
    lw[4]=r1.x;  lw[5]=r1.y;  lw[6]=r1.z;  lw[7]=r1.w;
    lw[8]=r2.x;  lw[9]=r2.y;  lw[10]=r2.z; lw[11]=r2.w;
    lw[12]=r3.x; lw[13]=r3.y; lw[14]=r3.z; lw[15]=r3.w;
    __syncthreads();
    uint4* dst = reinterpret_cast<uint4*>(V4 + (size_t)bh * LSEQ * DK + (size_t)s0 * DK);
    #pragma unroll
    for (int p = 0; p < 4; ++p) {
        const int u = t + 256 * p;              // uint4 index within this 8-kt chunk
        const int ktl = u >> 7;
        const int j = (u >> 6) & 1;
        const int lane = u & 63;
        const int d = lane & 31;
        const int h2 = lane >> 5;
        const int krow = ktl * 32 + 16 * j + 8 * h2;
        unsigned ow[4];
        #pragma unroll
        for (int m = 0; m < 4; ++m) {
            unsigned lo  = lsd[krow + 2*m][d];
            unsigned hi2 = lsd[krow + 2*m + 1][d];
            ow[m] = lo | (hi2 << 16);
        }
        dst[u] = make_uint4(ow[0], ow[1], ow[2], ow[3]);
    }
}

// ---------- kernel 2: fused MFMA flash attention + output projection ----------
// 1-D grid with b = id&7 so each batch's 64 blocks land on ONE XCD (T1):
// that XCD's 4MB L2 then holds the batch's 512KB K/V -> L2-local re-reads.
__global__ __launch_bounds__(512, 4) void attnproj_kernel(
    const unsigned short* __restrict__ Qb, const unsigned short* __restrict__ Kb,
    const unsigned short* __restrict__ V4, const float* __restrict__ mask,
    const int* __restrict__ cnt, const float* __restrict__ Wo,
    float* __restrict__ out)
{
    const int b = blockIdx.x & 7;                 // XCD-pinned batch
    const int q0 = (blockIdx.x >> 3) * 32;
    const int tid = threadIdx.x;
    const int wid = tid >> 6;                     // 8 waves
    const int h = wid >> 1;                       // head
    const int kw = wid & 1;                       // key-half owner
    const int lane = tid & 63;
    const int ql = lane & 31;
    const int hi = lane >> 5;
    const int bh = b * NH + h;
    const int n = cnt[b];

    __shared__ __align__(16) char smem[17408];
    float* red = reinterpret_cast<float*>(smem);                  // [4][64][17]
    unsigned short* hd = reinterpret_cast<unsigned short*>(smem); // [32][136]

    const uint4* Qp = reinterpret_cast<const uint4*>(Qb + ((size_t)bh * LSEQ + q0 + ql) * DK);
    const bf16x8 qf0 = as_bf16x8(Qp[hi]);         // Q[q=ql][d=8*hi+i] (pre-scaled)
    const bf16x8 qf1 = as_bf16x8(Qp[2 + hi]);

    const unsigned short* Kbase = Kb + (size_t)bh * LSEQ * DK;
    const unsigned short* Vb4   = V4 + (size_t)bh * LSEQ * DK;

    f32x16 acc;
    #pragma unroll
    for (int r = 0; r < 16; ++r) acc[r] = 0.f;
    f32x16 zero;
    #pragma unroll
    for (int r = 0; r < 16; ++r) zero[r] = 0.f;
    float la0 = 0.f, la1 = 0.f;

    auto ldk0 = [&](int k) { return reinterpret_cast<const uint4*>(Kbase + (size_t)(k + ql) * DK)[hi]; };
    auto ldk1 = [&](int k) { return reinterpret_cast<const uint4*>(Kbase + (size_t)(k + ql) * DK)[2 + hi]; };
    auto ldv0 = [&](int k) { return reinterpret_cast<const uint4*>(Vb4 + (size_t)(k >> 5) * 1024)[lane]; };
    auto ldv1 = [&](int k) { return reinterpret_cast<const uint4*>(Vb4 + (size_t)(k >> 5) * 1024)[64 + lane]; };

    auto compute = [&](uint4 kv0, uint4 kv1, uint4 vv0, uint4 vv1, int k0, bool pred) {
        f32x16 s = __builtin_amdgcn_mfma_f32_32x32x16_bf16(as_bf16x8(kv0), qf0, zero, 0, 0, 0);
        s = __builtin_amdgcn_mfma_f32_32x32x16_bf16(as_bf16x8(kv1), qf1, s, 0, 0, 0);
        unsigned w[8];
        #pragma unroll
        for (int j = 0; j < 8; ++j) {
            float e0 = exp2f(s[2*j]);             // key = k0+(r&3)+8*(r>>2)+4*hi
            float e1 = exp2f(s[2*j+1]);
            if (pred) {
                const int r0 = 2*j, r1 = 2*j + 1;
                if (k0 + (r0 & 3) + 8*(r0 >> 2) + 4*hi >= n) e0 = 0.f;
                if (k0 + (r1 & 3) + 8*(r1 >> 2) + 4*hi >= n) e1 = 0.f;
            }
            la0 += e0;
            la1 += e1;
            w[j] = pack_bf2(e0, e1);
        }
        uint2v p0 = __builtin_amdgcn_permlane32_swap(w[0], w[2], false, false);
        uint2v p1 = __builtin_amdgcn_permlane32_swap(w[1], w[3], false, false);
        uint2v p2 = __builtin_amdgcn_permlane32_swap(w[4], w[6], false, false);
        uint2v p3 = __builtin_amdgcn_permlane32_swap(w[5], w[7], false, false);
        uint4 b0 = make_uint4(p0[0], p1[0], p0[1], p1[1]);
        uint4 b1 = make_uint4(p2[0], p3[0], p2[1], p3[1]);
        acc = __builtin_amdgcn_mfma_f32_32x32x16_bf16(as_bf16x8(vv0), as_bf16x8(b0), acc, 0, 0, 0);
        acc = __builtin_amdgcn_mfma_f32_32x32x16_bf16(as_bf16x8(vv1), as_bf16x8(b1), acc, 0, 0, 0);
    };

    const int nfull = n & ~31;
    int k = kw * 32;
    if (k < nfull) {
        uint4 ka0 = ldk0(k), ka1 = ldk1(k), va0 = ldv0(k), va1 = ldv1(k);
        for (; k + 64 < nfull; k += 64) {
            uint4 kb0 = ldk0(k + 64), kb1 = ldk1(k + 64);
            uint4 vb0 = ldv0(k + 64), vb1 = ldv1(k + 64);
            compute(ka0, ka1, va0, va1, k, false);
            ka0 = kb0; ka1 = kb1; va0 = vb0; va1 = vb1;
        }
        compute(ka0, ka1, va0, va1, k, false);
    }
    if ((n & 31) && (((nfull >> 5) & 1) == kw)) {
        uint4 ka0 = ldk0(nfull), ka1 = ldk1(nfull);
        uint4 va0 = ldv0(nfull), va1 = ldv1(nfull);
        compute(ka0, ka1, va0, va1, nfull, true);
    }

    float la = la0 + la1;

    // ---- merge the two key-half partials (one LDS round) ----
    if (kw == 1) {
        float* r0 = red + ((size_t)h * 64 + lane) * 17;
        #pragma unroll
        for (int r = 0; r < 16; ++r) r0[r] = acc[r];
        r0[16] = la;
    }
    __syncthreads();
    float wgt = 0.f;
    if (kw == 0) {
        const float* r0 = red + ((size_t)h * 64 + lane) * 17;
        #pragma unroll
        for (int r = 0; r < 16; ++r) acc[r] += r0[r];
        la += r0[16];
        const float lf = la + __shfl_xor(la, 32);
        const float mq = mask[(size_t)b * LSEQ + q0 + ql];
        wgt = (lf > 0.f) ? (mq / lf) : 0.f;
    }
    __syncthreads();                              // red dead; reuse as hd

    // ---- stage normalized O-tile (32 q x 128 d) in LDS as bf16 ----
    if (kw == 0) {
        unsigned short* hrow = hd + ql * 136 + h * DK + 4 * hi;
        #pragma unroll
        for (int g = 0; g < 4; ++g) {             // d = 8g + 4hi + (0..3)
            uint2 p = make_uint2(pack_bf2(acc[4*g+0]*wgt, acc[4*g+1]*wgt),
                                 pack_bf2(acc[4*g+2]*wgt, acc[4*g+3]*wgt));
            *reinterpret_cast<uint2*>(hrow + 8*g) = p;
        }
    }
    __syncthreads();

    // ---- output projection: waves 0-3, one j-quarter each ----
    if (wid < 4) {
        const int jq = wid;
        f32x16 pacc;
        #pragma unroll
        for (int r = 0; r < 16; ++r) pacc[r] = 0.f;
        #pragma unroll
        for (int ks = 0; ks < 8; ++ks) {
            const int k0 = ks * 16 + 8 * hi;
            uint4 bp = *reinterpret_cast<const uint4*>(hd + ql * 136 + k0);  // Hd[l][k0..k0+7]
            const float* wcol = Wo + (size_t)k0 * DM + jq * 32 + ql;         // Wo[k][j]
            float w[8];
            #pragma unroll
            for (int i = 0; i < 8; ++i) w[i] = wcol[(size_t)i * DM];
            uint4 ap = make_uint4(pack_bf2(w[0], w[1]), pack_bf2(w[2], w[3]),
                                  pack_bf2(w[4], w[5]), pack_bf2(w[6], w[7]));
            pacc = __builtin_amdgcn_mfma_f32_32x32x16_bf16(as_bf16x8(ap), as_bf16x8(bp), pacc, 0, 0, 0);
        }
        float* obase = out + (size_t)b * DM * LSEQ + q0 + ql;
        #pragma unroll
        for (int r = 0; r < 16; ++r) {
            const int j = jq * 32 + (r & 3) + 8 * (r >> 2) + 4 * hi;
            obase[(size_t)j * LSEQ] = pacc[r];    // coalesced across ql
        }
    }
}

extern "C" void kernel_launch(void* const* d_in, const int* in_sizes, int n_in,
                              void* d_out, int out_size, void* d_ws, size_t ws_size,
                              hipStream_t stream)
{
    const float* x    = (const float*)d_in[0];
    const float* mask = (const float*)d_in[1];
    const float* Wq   = (const float*)d_in[2];
    const float* Wk   = (const float*)d_in[3];
    const float* Wv   = (const float*)d_in[4];
    const float* Wo   = (const float*)d_in[5];
    float* out = (float*)d_out;

    char* wsb = (char*)d_ws;
    const size_t NBF = (size_t)BATCH * NH * LSEQ * DK;      // 2,097,152 elems
    unsigned short* Qb  = (unsigned short*)wsb;             // 4MB
    unsigned short* Kb  = Qb + NBF;                         // 4MB
    unsigned short* Vcb = Kb + NBF;                         // 4MB
    unsigned short* V4  = Vcb + NBF;                        // 4MB frag-layout V
    int* cnt  = (int*)(wsb + 24ull * 1024 * 1024);

    qkv_mfma_kernel<<<dim3(BATCH, 3, LSEQ / 64), dim3(256), 0, stream>>>(
        x, Wq, Wk, Wv, mask, Qb, Kb, Vcb, cnt);
    vfrag_kernel<<<dim3(LSEQ / 256, BATCH * NH), dim3(256), 0, stream>>>(Vcb, V4);
    attnproj_kernel<<<dim3(BATCH * LSEQ / 32), dim3(512), 0, stream>>>(
        Qb, Kb, V4, mask, cnt, Wo, out);
}

// Round 13
// 43.351 us; speedup vs baseline: 1.3176x; 1.0696x over previous
//
#include <hip/hip_runtime.h>
#include <hip/hip_bf16.h>
#include <math.h>

#define BATCH 8
#define LSEQ 2048
#define DM 128
#define NH 4
#define DK 32

constexpr float SCALE = 0.17677669529663687f;   // 1/sqrt(32)
constexpr float LOG2E = 1.4426950408889634f;
constexpr float SL = SCALE * LOG2E;             // folded into Q at qkv store

typedef __attribute__((ext_vector_type(8))) __bf16 bf16x8;
typedef __attribute__((ext_vector_type(16))) float f32x16;
typedef __attribute__((ext_vector_type(2))) unsigned uint2v;

__device__ __forceinline__ bf16x8 as_bf16x8(uint4 u) {
    union { uint4 a; bf16x8 b; } c; c.a = u; return c.b;
}
__device__ __forceinline__ unsigned pack_bf2(float lo, float hi) {
    __hip_bfloat162 h = __float22bfloat162_rn(make_float2(lo, hi));
    union { __hip_bfloat162 a; unsigned b; } c; c.a = h; return c.b;
}
__device__ __forceinline__ unsigned short bf16u(float f) {
    union { __hip_bfloat16 h; unsigned short u; } c; c.h = __float2bfloat16(f); return c.u;
}

// ---------- kernel 1: QKV projection via MFMA, fused mask-scan, LDS-staged W ----------
// Q is pre-scaled by SCALE*LOG2E so attn can exp2 scores directly.
// W (all 4 heads, 16K floats) staged ONCE into LDS in MFMA-A-fragment order;
// hot loop reads two A-frags as conflict-free ds_read_b128.
// V results are scattered DIRECTLY into the V4 fragment layout (u16 stores):
// elem (key=s, d) -> (s>>5)*1024 + ((s>>4)&1)*512 + ((s>>3)&1)*256 + d*8 + (s&7).
__global__ __launch_bounds__(256) void qkv_mfma_kernel(const float* __restrict__ x,
    const float* __restrict__ Wq, const float* __restrict__ Wk, const float* __restrict__ Wv,
    const float* __restrict__ mask,
    unsigned short* __restrict__ Qb, unsigned short* __restrict__ Kb,
    unsigned short* __restrict__ V4, int* __restrict__ cnt)
{
    const int b = blockIdx.x;                 // 8
    const int which = blockIdx.y;             // 0=Q 1=K 2=V
    const int lt = blockIdx.z;                // 32 tiles of 64 l
    const int tid = threadIdx.x;
    const int wv = tid >> 6;                  // 4 waves
    const int lane = tid & 63;
    const int ql = lane & 31;
    const int hi = lane >> 5;
    const int l = lt * 64 + (wv & 1) * 32 + ql;   // this lane's output row
    const int hbase = (wv >> 1) * 2;              // head pair

    __shared__ unsigned short wl[4][16][32][8];   // 32KB: [h][d/8][dk][d%8]
    __shared__ int slotbuf[64];
    __shared__ int wsumI[4];

    const float* W = (which == 0 ? Wq : (which == 1 ? Wk : Wv));

    // ---- one-time W stage: 16384 floats, coalesced float4, frag-order bf16 ----
    #pragma unroll
    for (int it = 0; it < 16; ++it) {
        const int flat = (it * 256 + tid) * 4;    // float index into W[which]
        float4 v = *reinterpret_cast<const float4*>(W + flat);
        const int dk0 = flat & 31;
        const int d   = (flat >> 5) & 127;
        const int h   = flat >> 12;
        wl[h][d >> 3][dk0 + 0][d & 7] = bf16u(v.x);
        wl[h][d >> 3][dk0 + 1][d & 7] = bf16u(v.y);
        wl[h][d >> 3][dk0 + 2][d & 7] = bf16u(v.z);
        wl[h][d >> 3][dk0 + 3][d & 7] = bf16u(v.w);
    }

    // ---- fused scan (K/V blocks only; block-uniform branch) ----
    if (which != 0) {
        const int nchunk = (lt + 1) * 8;          // 8-elem chunks cover [0, (lt+1)*64)
        int c = 0;
        if (tid < nchunk) {
            const float* mb = mask + (size_t)b * LSEQ + tid * 8;
            #pragma unroll
            for (int i = 0; i < 8; ++i) c += (mb[i] == 0.0f) ? 1 : 0;
        }
        int inc = c;                               // wave-inclusive scan (64 lanes)
        #pragma unroll
        for (int off = 1; off < 64; off <<= 1) {
            int v = __shfl_up(inc, off);
            if (lane >= off) inc += v;
        }
        if (lane == 63) wsumI[wv] = inc;
        __syncthreads();
        int wpre = 0;
        #pragma unroll
        for (int wN = 0; wN < 4; ++wN) if (wN < wv) wpre += wsumI[wN];
        const int excl = wpre + inc - c;           // exclusive prefix of chunk tid
        if (tid >= lt * 8 && tid < lt * 8 + 8) {   // chunks covering this block's 64 l's
            const float* mb = mask + (size_t)b * LSEQ + tid * 8;
            int run = excl;
            #pragma unroll
            for (int i = 0; i < 8; ++i) {
                slotbuf[(tid - lt * 8) * 8 + i] = run;
                run += (mb[i] == 0.0f) ? 1 : 0;
            }
        }
        if (which == 1 && lt == 31 && tid == 255) cnt[b] = wpre + inc;  // total zeros
    }
    __syncthreads();                               // covers W stage (+scan)

    const float* xcol = x + (size_t)b * DM * LSEQ + l;   // x[b][d][l]

    f32x16 acc0, acc1;
    #pragma unroll
    for (int r = 0; r < 16; ++r) { acc0[r] = 0.f; acc1[r] = 0.f; }

    #pragma unroll
    for (int d0 = 0; d0 < DM; d0 += 16) {
        const int dblk = (d0 >> 3) + hi;
        float xv[8];
        #pragma unroll
        for (int i = 0; i < 8; ++i) xv[i] = xcol[(size_t)(d0 + 8 * hi + i) * LSEQ];
        uint4 xp = make_uint4(pack_bf2(xv[0], xv[1]), pack_bf2(xv[2], xv[3]),
                              pack_bf2(xv[4], xv[5]), pack_bf2(xv[6], xv[7]));
        const bf16x8 xf = as_bf16x8(xp);
        uint4 wp0 = *reinterpret_cast<const uint4*>(&wl[hbase + 0][dblk][ql][0]);
        uint4 wp1 = *reinterpret_cast<const uint4*>(&wl[hbase + 1][dblk][ql][0]);
        acc0 = __builtin_amdgcn_mfma_f32_32x32x16_bf16(as_bf16x8(wp0), xf, acc0, 0, 0, 0);
        acc1 = __builtin_amdgcn_mfma_f32_32x32x16_bf16(as_bf16x8(wp1), xf, acc1, 0, 0, 0);
    }

    bool store = true;
    int slot = l;
    if (which != 0) {
        if (mask[(size_t)b * LSEQ + l] == 0.0f) slot = slotbuf[(wv & 1) * 32 + ql];
        else store = false;
    }
    if (store) {
        if (which < 2) {
            // Q (pre-scaled) or K: row-major pair stores
            const float fold = (which == 0) ? SL : 1.0f;
            unsigned short* base0 = (which == 0 ? Qb : Kb);
            #pragma unroll
            for (int hh = 0; hh < 2; ++hh) {
                const f32x16& A = hh ? acc1 : acc0;
                const int bh = b * NH + hbase + hh;
                unsigned short* rowp = base0 + ((size_t)bh * LSEQ + slot) * DK;
                unsigned dw[8];
                #pragma unroll
                for (int j = 0; j < 8; ++j) dw[j] = pack_bf2(A[2*j] * fold, A[2*j+1] * fold);
                *reinterpret_cast<uint2*>(rowp + 4*hi)      = make_uint2(dw[0], dw[1]);
                *reinterpret_cast<uint2*>(rowp + 8 + 4*hi)  = make_uint2(dw[2], dw[3]);
                *reinterpret_cast<uint2*>(rowp + 16 + 4*hi) = make_uint2(dw[4], dw[5]);
                *reinterpret_cast<uint2*>(rowp + 24 + 4*hi) = make_uint2(dw[6], dw[7]);
            }
        } else {
            // V: direct scatter into V4 fragment layout.
            // A[r] holds d = 4*hi + (r&3) + 8*(r>>2); u16 offset = sbase + d*8
            // with sbase folding the slot decomposition and the 4*hi*8 term.
            const int sbase = (slot >> 5) * 1024 + ((slot >> 4) & 1) * 512
                            + ((slot >> 3) & 1) * 256 + (slot & 7) + hi * 32;
            #pragma unroll
            for (int hh = 0; hh < 2; ++hh) {
                const f32x16& A = hh ? acc1 : acc0;
                const int bh = b * NH + hbase + hh;
                unsigned short* vb = V4 + (size_t)bh * (LSEQ * DK) + sbase;
                #pragma unroll
                for (int r = 0; r < 16; ++r)
                    vb[8 * (r & 3) + 64 * (r >> 2)] = bf16u(A[r]);
            }
        }
    }
}

// ---------- kernel 2: fused MFMA flash attention + output projection ----------
// 1-D grid with b = id&7 so each batch's 64 blocks land on ONE XCD (T1):
// that XCD's 4MB L2 then holds the batch's 512KB K/V -> L2-local re-reads.
__global__ __launch_bounds__(512, 4) void attnproj_kernel(
    const unsigned short* __restrict__ Qb, const unsigned short* __restrict__ Kb,
    const unsigned short* __restrict__ V4, const float* __restrict__ mask,
    const int* __restrict__ cnt, const float* __restrict__ Wo,
    float* __restrict__ out)
{
    const int b = blockIdx.x & 7;                 // XCD-pinned batch
    const int q0 = (blockIdx.x >> 3) * 32;
    const int tid = threadIdx.x;
    const int wid = tid >> 6;                     // 8 waves
    const int h = wid >> 1;                       // head
    const int kw = wid & 1;                       // key-half owner
    const int lane = tid & 63;
    const int ql = lane & 31;
    const int hi = lane >> 5;
    const int bh = b * NH + h;
    const int n = cnt[b];

    __shared__ __align__(16) char smem[17408];
    float* red = reinterpret_cast<float*>(smem);                  // [4][64][17]
    unsigned short* hd = reinterpret_cast<unsigned short*>(smem); // [32][136]

    const uint4* Qp = reinterpret_cast<const uint4*>(Qb + ((size_t)bh * LSEQ + q0 + ql) * DK);
    const bf16x8 qf0 = as_bf16x8(Qp[hi]);         // Q[q=ql][d=8*hi+i] (pre-scaled)
    const bf16x8 qf1 = as_bf16x8(Qp[2 + hi]);

    const unsigned short* Kbase = Kb + (size_t)bh * LSEQ * DK;
    const unsigned short* Vb4   = V4 + (size_t)bh * LSEQ * DK;

    f32x16 acc;
    #pragma unroll
    for (int r = 0; r < 16; ++r) acc[r] = 0.f;
    f32x16 zero;
    #pragma unroll
    for (int r = 0; r < 16; ++r) zero[r] = 0.f;
    float la0 = 0.f, la1 = 0.f;

    auto ldk0 = [&](int k) { return reinterpret_cast<const uint4*>(Kbase + (size_t)(k + ql) * DK)[hi]; };
    auto ldk1 = [&](int k) { return reinterpret_cast<const uint4*>(Kbase + (size_t)(k + ql) * DK)[2 + hi]; };
    auto ldv0 = [&](int k) { return reinterpret_cast<const uint4*>(Vb4 + (size_t)(k >> 5) * 1024)[lane]; };
    auto ldv1 = [&](int k) { return reinterpret_cast<const uint4*>(Vb4 + (size_t)(k >> 5) * 1024)[64 + lane]; };

    auto compute = [&](uint4 kv0, uint4 kv1, uint4 vv0, uint4 vv1, int k0, bool pred) {
        f32x16 s = __builtin_amdgcn_mfma_f32_32x32x16_bf16(as_bf16x8(kv0), qf0, zero, 0, 0, 0);
        s = __builtin_amdgcn_mfma_f32_32x32x16_bf16(as_bf16x8(kv1), qf1, s, 0, 0, 0);
        unsigned w[8];
        #pragma unroll
        for (int j = 0; j < 8; ++j) {
            float e0 = exp2f(s[2*j]);             // key = k0+(r&3)+8*(r>>2)+4*hi
            float e1 = exp2f(s[2*j+1]);
            if (pred) {
                const int r0 = 2*j, r1 = 2*j + 1;
                if (k0 + (r0 & 3) + 8*(r0 >> 2) + 4*hi >= n) e0 = 0.f;
                if (k0 + (r1 & 3) + 8*(r1 >> 2) + 4*hi >= n) e1 = 0.f;
            }
            la0 += e0;
            la1 += e1;
            w[j] = pack_bf2(e0, e1);
        }
        uint2v p0 = __builtin_amdgcn_permlane32_swap(w[0], w[2], false, false);
        uint2v p1 = __builtin_amdgcn_permlane32_swap(w[1], w[3], false, false);
        uint2v p2 = __builtin_amdgcn_permlane32_swap(w[4], w[6], false, false);
        uint2v p3 = __builtin_amdgcn_permlane32_swap(w[5], w[7], false, false);
        uint4 b0 = make_uint4(p0[0], p1[0], p0[1], p1[1]);
        uint4 b1 = make_uint4(p2[0], p3[0], p2[1], p3[1]);
        acc = __builtin_amdgcn_mfma_f32_32x32x16_bf16(as_bf16x8(vv0), as_bf16x8(b0), acc, 0, 0, 0);
        acc = __builtin_amdgcn_mfma_f32_32x32x16_bf16(as_bf16x8(vv1), as_bf16x8(b1), acc, 0, 0, 0);
    };

    const int nfull = n & ~31;
    int k = kw * 32;
    if (k < nfull) {
        uint4 ka0 = ldk0(k), ka1 = ldk1(k), va0 = ldv0(k), va1 = ldv1(k);
        for (; k + 64 < nfull; k += 64) {
            uint4 kb0 = ldk0(k + 64), kb1 = ldk1(k + 64);
            uint4 vb0 = ldv0(k + 64), vb1 = ldv1(k + 64);
            compute(ka0, ka1, va0, va1, k, false);
            ka0 = kb0; ka1 = kb1; va0 = vb0; va1 = vb1;
        }
        compute(ka0, ka1, va0, va1, k, false);
    }
    if ((n & 31) && (((nfull >> 5) & 1) == kw)) {
        uint4 ka0 = ldk0(nfull), ka1 = ldk1(nfull);
        uint4 va0 = ldv0(nfull), va1 = ldv1(nfull);
        compute(ka0, ka1, va0, va1, nfull, true);
    }

    float la = la0 + la1;

    // ---- merge the two key-half partials (one LDS round) ----
    if (kw == 1) {
        float* r0 = red + ((size_t)h * 64 + lane) * 17;
        #pragma unroll
        for (int r = 0; r < 16; ++r) r0[r] = acc[r];
        r0[16] = la;
    }
    __syncthreads();
    float wgt = 0.f;
    if (kw == 0) {
        const float* r0 = red + ((size_t)h * 64 + lane) * 17;
        #pragma unroll
        for (int r = 0; r < 16; ++r) acc[r] += r0[r];
        la += r0[16];
        const float lf = la + __shfl_xor(la, 32);
        const float mq = mask[(size_t)b * LSEQ + q0 + ql];
        wgt = (lf > 0.f) ? (mq / lf) : 0.f;
    }
    __syncthreads();                              // red dead; reuse as hd

    // ---- stage normalized O-tile (32 q x 128 d) in LDS as bf16 ----
    if (kw == 0) {
        unsigned short* hrow = hd + ql * 136 + h * DK + 4 * hi;
        #pragma unroll
        for (int g = 0; g < 4; ++g) {             // d = 8g + 4hi + (0..3)
            uint2 p = make_uint2(pack_bf2(acc[4*g+0]*wgt, acc[4*g+1]*wgt),
                                 pack_bf2(acc[4*g+2]*wgt, acc[4*g+3]*wgt));
            *reinterpret_cast<uint2*>(hrow + 8*g) = p;
        }
    }
    __syncthreads();

    // ---- output projection: waves 0-3, one j-quarter each ----
    if (wid < 4) {
        const int jq = wid;
        f32x16 pacc;
        #pragma unroll
        for (int r = 0; r < 16; ++r) pacc[r] = 0.f;
        #pragma unroll
        for (int ks = 0; ks < 8; ++ks) {
            const int k0 = ks * 16 + 8 * hi;
            uint4 bp = *reinterpret_cast<const uint4*>(hd + ql * 136 + k0);  // Hd[l][k0..k0+7]
            const float* wcol = Wo + (size_t)k0 * DM + jq * 32 + ql;         // Wo[k][j]
            float w[8];
            #pragma unroll
            for (int i = 0; i < 8; ++i) w[i] = wcol[(size_t)i * DM];
            uint4 ap = make_uint4(pack_bf2(w[0], w[1]), pack_bf2(w[2], w[3]),
                                  pack_bf2(w[4], w[5]), pack_bf2(w[6], w[7]));
            pacc = __builtin_amdgcn_mfma_f32_32x32x16_bf16(as_bf16x8(ap), as_bf16x8(bp), pacc, 0, 0, 0);
        }
        float* obase = out + (size_t)b * DM * LSEQ + q0 + ql;
        #pragma unroll
        for (int r = 0; r < 16; ++r) {
            const int j = jq * 32 + (r & 3) + 8 * (r >> 2) + 4 * hi;
            obase[(size_t)j * LSEQ] = pacc[r];    // coalesced across ql
        }
    }
}

extern "C" void kernel_launch(void* const* d_in, const int* in_sizes, int n_in,
                              void* d_out, int out_size, void* d_ws, size_t ws_size,
                              hipStream_t stream)
{
    const float* x    = (const float*)d_in[0];
    const float* mask = (const float*)d_in[1];
    const float* Wq   = (const float*)d_in[2];
    const float* Wk   = (const float*)d_in[3];
    const float* Wv   = (const float*)d_in[4];
    const float* Wo   = (const float*)d_in[5];
    float* out = (float*)d_out;

    char* wsb = (char*)d_ws;
    const size_t NBF = (size_t)BATCH * NH * LSEQ * DK;      // 2,097,152 elems
    unsigned short* Qb  = (unsigned short*)wsb;             // 4MB
    unsigned short* Kb  = Qb + NBF;                         // 4MB
    unsigned short* V4  = Kb + NBF;                         // 4MB frag-layout V
    int* cnt  = (int*)(wsb + 24ull * 1024 * 1024);

    qkv_mfma_kernel<<<dim3(BATCH, 3, LSEQ / 64), dim3(256), 0, stream>>>(
        x, Wq, Wk, Wv, mask, Qb, Kb, V4, cnt);
    attnproj_kernel<<<dim3(BATCH * LSEQ / 32), dim3(512), 0, stream>>>(
        Qb, Kb, V4, mask, cnt, Wo, out);
}